// Round 9
// baseline (279.531 us; speedup 1.0000x reference)
//
#include <hip/hip_runtime.h>

typedef __attribute__((ext_vector_type(8))) short bf16x8;
typedef __attribute__((ext_vector_type(4))) float f32x4;

// ---- split-bf16 helpers: value v ~ hi + lo, packed as (hi16<<16)|lo16 ----
__device__ __forceinline__ unsigned bfr16(float x) {            // RNE fp32->bf16 bits
    unsigned u = __float_as_uint(x);
    return (u + 0x7fffu + ((u >> 16) & 1u)) >> 16;
}
__device__ __forceinline__ unsigned pack_bf2(float v) {
    unsigned hr = bfr16(v);
    float lof = v - __uint_as_float(hr << 16);
    unsigned lr = bfr16(lof);
    return (hr << 16) | (lr & 0xffffu);
}
// bf16 pair decode (two ushorts in one u32)
__device__ __forceinline__ float lo16f(unsigned u) { return __uint_as_float(u << 16); }
__device__ __forceinline__ float hi16f(unsigned u) { return __uint_as_float(u & 0xffff0000u); }

union U8 { bf16x8 v; unsigned u[4]; };

// activation B-fragment from 8 consecutive packed u32 (sample = lane&15, k-slice = (lane>>4)*8)
__device__ __forceinline__ void frag_from_packed(const unsigned* ap, bf16x8& hi, bf16x8& lo) {
    uint4 u0 = *(const uint4*)ap;
    uint4 u1 = *(const uint4*)(ap + 4);
    U8 H, L;
    H.u[0] = __builtin_amdgcn_perm(u0.y, u0.x, 0x07060302u);
    H.u[1] = __builtin_amdgcn_perm(u0.w, u0.z, 0x07060302u);
    H.u[2] = __builtin_amdgcn_perm(u1.y, u1.x, 0x07060302u);
    H.u[3] = __builtin_amdgcn_perm(u1.w, u1.z, 0x07060302u);
    L.u[0] = __builtin_amdgcn_perm(u0.y, u0.x, 0x05040100u);
    L.u[1] = __builtin_amdgcn_perm(u0.w, u0.z, 0x05040100u);
    L.u[2] = __builtin_amdgcn_perm(u1.y, u1.x, 0x05040100u);
    L.u[3] = __builtin_amdgcn_perm(u1.w, u1.z, 0x05040100u);
    hi = H.v; lo = L.v;
}

__device__ __forceinline__ void frag_from_f32(const float* fp, bf16x8& hi, bf16x8& lo) {
    float4 f0 = *(const float4*)fp;
    float4 f1 = *(const float4*)(fp + 4);
    float fv[8] = {f0.x, f0.y, f0.z, f0.w, f1.x, f1.y, f1.z, f1.w};
    U8 H, L;
    #pragma unroll
    for (int p = 0; p < 4; p++) {
        float a = fv[2 * p], b = fv[2 * p + 1];
        unsigned ra = bfr16(a), rb = bfr16(b);
        H.u[p] = ra | (rb << 16);
        float la = a - __uint_as_float(ra << 16);
        float lb = b - __uint_as_float(rb << 16);
        L.u[p] = bfr16(la) | (bfr16(lb) << 16);
    }
    hi = H.v; lo = L.v;
}

// split staging: global -> registers (issue early), registers -> LDS (write late)
__device__ __forceinline__ void stage_load(uint4* wreg, const unsigned short* Wp, int t) {
    const uint4* src = (const uint4*)Wp;
    #pragma unroll
    for (int p = 0; p < 8; p++) wreg[p] = src[t + p * 512];
}
__device__ __forceinline__ void stage_write(unsigned short* sm, const uint4* wreg, int t) {
    uint4* dst = (uint4*)sm;
    #pragma unroll
    for (int p = 0; p < 8; p++) dst[t + p * 512] = wreg[p];
}

// weight A-operand fragment pair from LDS (hi at 0, lo at +16384 u16)
__device__ __forceinline__ void wfrag_lds(const unsigned short* sm, int f, int lane,
                                          bf16x8& whi, bf16x8& wlo) {
    whi = *(const bf16x8*)(sm + f * 512 + lane * 8);
    wlo = *(const bf16x8*)(sm + 16384 + f * 512 + lane * 8);
}

#define MFMA3(accv, whi, wlo, yhi, ylo)                                              \
    accv = __builtin_amdgcn_mfma_f32_16x16x32_bf16(whi, yhi, accv, 0, 0, 0);         \
    accv = __builtin_amdgcn_mfma_f32_16x16x32_bf16(whi, ylo, accv, 0, 0, 0);         \
    accv = __builtin_amdgcn_mfma_f32_16x16x32_bf16(wlo, yhi, accv, 0, 0, 0);

// slot->true-channel map: chan(nt, rho=4g+r) = 32*(nt>>1) + 8*g + 4*(nt&1) + r
// self-consistent: B-frag built as acc[2kt+(j>>2)][j&3] reads true channel kt*32+g*8+j.

// layer transition entirely in registers: y(kt) fragment from acc + bias (+relu)
__device__ __forceinline__ void trans_frag(const f32x4* acc, float4 bva, float4 bvb, int kt,
                                           bf16x8& yh, bf16x8& yl) {
    const int n0 = 2 * kt, n1 = n0 + 1;
    float v0 = fmaxf(acc[n0][0] + bva.x, 0.f);
    float v1 = fmaxf(acc[n0][1] + bva.y, 0.f);
    float v2 = fmaxf(acc[n0][2] + bva.z, 0.f);
    float v3 = fmaxf(acc[n0][3] + bva.w, 0.f);
    float v4 = fmaxf(acc[n1][0] + bvb.x, 0.f);
    float v5 = fmaxf(acc[n1][1] + bvb.y, 0.f);
    float v6 = fmaxf(acc[n1][2] + bvb.z, 0.f);
    float v7 = fmaxf(acc[n1][3] + bvb.w, 0.f);
    U8 H, L;
    unsigned ra, rb;
    ra = bfr16(v0); rb = bfr16(v1);
    H.u[0] = ra | (rb << 16);
    L.u[0] = bfr16(v0 - __uint_as_float(ra << 16)) | (bfr16(v1 - __uint_as_float(rb << 16)) << 16);
    ra = bfr16(v2); rb = bfr16(v3);
    H.u[1] = ra | (rb << 16);
    L.u[1] = bfr16(v2 - __uint_as_float(ra << 16)) | (bfr16(v3 - __uint_as_float(rb << 16)) << 16);
    ra = bfr16(v4); rb = bfr16(v5);
    H.u[2] = ra | (rb << 16);
    L.u[2] = bfr16(v4 - __uint_as_float(ra << 16)) | (bfr16(v5 - __uint_as_float(rb << 16)) << 16);
    ra = bfr16(v6); rb = bfr16(v7);
    H.u[3] = ra | (rb << 16);
    L.u[3] = bfr16(v6 - __uint_as_float(ra << 16)) | (bfr16(v7 - __uint_as_float(rb << 16)) << 16);
    yh = H.v; yl = L.v;
}

// ---------------- CSR build ----------------

__global__ void zero2_k(int* __restrict__ a, int* __restrict__ b, int n) {
    int i = blockIdx.x * blockDim.x + threadIdx.x;
    if (i < n) { a[i] = 0; b[i] = 0; }
}

__global__ void hist_k(const int* __restrict__ dst, int* __restrict__ deg, int E) {
    int e = blockIdx.x * blockDim.x + threadIdx.x;
    if (e < E) atomicAdd(&deg[dst[e]], 1);
}

__global__ void scan1_k(const int* __restrict__ deg, int* __restrict__ rowptr,
                        int* __restrict__ bsum, float* __restrict__ dinv, int n) {
    __shared__ int s[256];
    int tid = threadIdx.x;
    int i = blockIdx.x * 256 + tid;
    int v = (i < n) ? deg[i] : 0;
    s[tid] = v;
    __syncthreads();
    #pragma unroll
    for (int off = 1; off < 256; off <<= 1) {
        int t = (tid >= off) ? s[tid - off] : 0;
        __syncthreads();
        s[tid] += t;
        __syncthreads();
    }
    if (i < n) {
        rowptr[i] = s[tid] - v;
        dinv[i] = rsqrtf((float)(v + 1));
    }
    if (tid == 255) bsum[blockIdx.x] = s[255];
}

__global__ void scan2_k(int* __restrict__ bsum, int nb) {
    __shared__ int s[512];
    int tid = threadIdx.x;
    int v = (tid < nb) ? bsum[tid] : 0;
    s[tid] = v;
    __syncthreads();
    #pragma unroll
    for (int off = 1; off < 512; off <<= 1) {
        int t = (tid >= off) ? s[tid - off] : 0;
        __syncthreads();
        s[tid] += t;
        __syncthreads();
    }
    if (tid < nb) bsum[tid] = s[tid] - v;
}

__global__ void scan3_k(int* __restrict__ rowptr, const int* __restrict__ bsum, int n) {
    int i = blockIdx.x * blockDim.x + threadIdx.x;
    if (i < n) rowptr[i] += bsum[i >> 8];
}

__global__ void place_k(const int* __restrict__ src, const int* __restrict__ dst,
                        const int* __restrict__ rowptr, int* __restrict__ cursor,
                        int* __restrict__ csr, int E) {
    int e = blockIdx.x * blockDim.x + threadIdx.x;
    if (e < E) {
        int d = dst[e];
        int pos = rowptr[d] + atomicAdd(&cursor[d], 1);
        csr[pos] = src[e];
    }
}

// ---- weight prep: W[k][c] -> A-operand frag (slot-permuted columns) ----
__global__ void wprep6_k(const float* __restrict__ s0, const float* __restrict__ s1,
                         const float* __restrict__ s2, const float* __restrict__ s3,
                         const float* __restrict__ s4, const float* __restrict__ s5,
                         unsigned short* __restrict__ dstBase) {
    const float* W;
    switch (blockIdx.y) {
        case 0: W = s0; break; case 1: W = s1; break; case 2: W = s2; break;
        case 3: W = s3; break; case 4: W = s4; break; default: W = s5; break;
    }
    unsigned short* out = dstBase + (size_t)blockIdx.y * 32768;
    int idx = blockIdx.x * 256 + threadIdx.x;
    if (idx >= 16384) return;
    int k = idx >> 7, c = idx & 127;
    float v = W[k * 128 + c];
    unsigned hr = bfr16(v);
    float lof = v - __uint_as_float(hr << 16);
    unsigned lr = bfr16(lof);
    int kt = k >> 5, gk = (k >> 3) & 3, j = k & 7;
    int nt = ((c >> 5) << 1) | ((c >> 2) & 1);
    int rho = (((c >> 3) & 3) << 2) | (c & 3);
    int lane = (gk << 4) | rho;
    int pos = (kt * 8 + nt) * 512 + lane * 8 + j;
    out[pos] = (unsigned short)hr;
    out[16384 + pos] = (unsigned short)lr;
}

// ---- gather aggregate: out[i] = relu(bias + dinv[i]*(hp[i] + sum_in hp[s])).
// hp is a bf16 hi-plane (2 B/chan). 4 nodes/wave, 16 lanes x 8 channels per node;
// 8-deep unrolled neighbor loop for outstanding-load depth. Output packed split-bf16.
__global__ __launch_bounds__(256)
void gather4_k(const unsigned short* __restrict__ hp, const float* __restrict__ dinv,
               const int* __restrict__ rowptr, const int* __restrict__ deg,
               const int* __restrict__ csr, const float* __restrict__ bias,
               unsigned* __restrict__ out, int N)
{
    int tid = threadIdx.x;
    int lane = tid & 63;
    int grp = lane >> 4, cl = lane & 15;
    int i = blockIdx.x * 16 + (tid >> 6) * 4 + grp;
    if (i >= N) return;
    int c8 = cl * 8;
    uint4 p = *(const uint4*)(hp + (size_t)i * 128 + c8);
    float a0 = lo16f(p.x), a1 = hi16f(p.x), a2 = lo16f(p.y), a3 = hi16f(p.y);
    float a4 = lo16f(p.z), a5 = hi16f(p.z), a6 = lo16f(p.w), a7 = hi16f(p.w);
    int beg = rowptr[i], dg = deg[i];
    int j = 0;
    for (; j + 7 < dg; j += 8) {
        uint4 q[8];
        #pragma unroll
        for (int u = 0; u < 8; u++) {
            int su = csr[beg + j + u];
            q[u] = *(const uint4*)(hp + (size_t)su * 128 + c8);
        }
        #pragma unroll
        for (int u = 0; u < 8; u++) {
            a0 += lo16f(q[u].x); a1 += hi16f(q[u].x);
            a2 += lo16f(q[u].y); a3 += hi16f(q[u].y);
            a4 += lo16f(q[u].z); a5 += hi16f(q[u].z);
            a6 += lo16f(q[u].w); a7 += hi16f(q[u].w);
        }
    }
    for (; j + 3 < dg; j += 4) {
        uint4 q[4];
        #pragma unroll
        for (int u = 0; u < 4; u++) {
            int su = csr[beg + j + u];
            q[u] = *(const uint4*)(hp + (size_t)su * 128 + c8);
        }
        #pragma unroll
        for (int u = 0; u < 4; u++) {
            a0 += lo16f(q[u].x); a1 += hi16f(q[u].x);
            a2 += lo16f(q[u].y); a3 += hi16f(q[u].y);
            a4 += lo16f(q[u].z); a5 += hi16f(q[u].z);
            a6 += lo16f(q[u].w); a7 += hi16f(q[u].w);
        }
    }
    for (; j < dg; j++) {
        int s0 = csr[beg + j];
        uint4 q0 = *(const uint4*)(hp + (size_t)s0 * 128 + c8);
        a0 += lo16f(q0.x); a1 += hi16f(q0.x); a2 += lo16f(q0.y); a3 += hi16f(q0.y);
        a4 += lo16f(q0.z); a5 += hi16f(q0.z); a6 += lo16f(q0.w); a7 += hi16f(q0.w);
    }
    float di = dinv[i];
    float4 bv0 = *(const float4*)(bias + c8);
    float4 bv1 = *(const float4*)(bias + c8 + 4);
    uint4 o0, o1;
    o0.x = pack_bf2(fmaxf(bv0.x + di * a0, 0.f));
    o0.y = pack_bf2(fmaxf(bv0.y + di * a1, 0.f));
    o0.z = pack_bf2(fmaxf(bv0.z + di * a2, 0.f));
    o0.w = pack_bf2(fmaxf(bv0.w + di * a3, 0.f));
    o1.x = pack_bf2(fmaxf(bv1.x + di * a4, 0.f));
    o1.y = pack_bf2(fmaxf(bv1.y + di * a5, 0.f));
    o1.z = pack_bf2(fmaxf(bv1.z + di * a6, 0.f));
    o1.w = pack_bf2(fmaxf(bv1.w + di * a7, 0.f));
    *(uint4*)(out + (size_t)i * 128 + c8) = o0;
    *(uint4*)(out + (size_t)i * 128 + c8 + 4) = o1;
}

// ---- layer GEMM: Chp = dinv-row-scaled (A @ W) as bf16 hi-plane.
// 2 sample-sets per wave (32 rows); W staged in LDS, shared by all 8 waves.
template<int AMODE>   // 0: A fp32 ; 1: A packed split-bf16
__global__ __launch_bounds__(512)
void rowgemm_k(const void* __restrict__ Asrc, const unsigned short* __restrict__ Wp,
               const float* __restrict__ rowScale, unsigned short* __restrict__ CoutHi, int M)
{
    __shared__ __align__(16) unsigned short smw[32768];   // 64 KB: one prepped weight matrix
    const int t = threadIdx.x, lane = t & 63, wave = t >> 6;
    const int base = blockIdx.x * 256 + wave * 32;
    const int s = lane & 15, g = lane >> 4, kg = g * 8;
    const int r0 = base + s, r1 = base + 16 + s;
    const int rc0 = (r0 < M) ? r0 : (M - 1);
    const int rc1 = (r1 < M) ? r1 : (M - 1);

    uint4 wreg[8];
    stage_load(wreg, Wp, t);
    stage_write(smw, wreg, t);

    // load A fragments while the staging lands
    bf16x8 yh[2][4], yl[2][4];
    #pragma unroll
    for (int kt = 0; kt < 4; kt++) {
        if (AMODE == 1) {
            frag_from_packed((const unsigned*)Asrc + (size_t)rc0 * 128 + kt * 32 + kg, yh[0][kt], yl[0][kt]);
            frag_from_packed((const unsigned*)Asrc + (size_t)rc1 * 128 + kt * 32 + kg, yh[1][kt], yl[1][kt]);
        } else {
            frag_from_f32((const float*)Asrc + (size_t)rc0 * 128 + kt * 32 + kg, yh[0][kt], yl[0][kt]);
            frag_from_f32((const float*)Asrc + (size_t)rc1 * 128 + kt * 32 + kg, yh[1][kt], yl[1][kt]);
        }
    }
    __syncthreads();

    f32x4 acc[2][8];
    #pragma unroll
    for (int st = 0; st < 2; st++)
        #pragma unroll
        for (int nt = 0; nt < 8; nt++) acc[st][nt] = (f32x4){0.f, 0.f, 0.f, 0.f};

    #pragma unroll
    for (int kt = 0; kt < 4; kt++) {
        #pragma unroll
        for (int nt = 0; nt < 8; nt++) {
            bf16x8 whi, wlo;
            wfrag_lds(smw, kt * 8 + nt, lane, whi, wlo);
            MFMA3(acc[0][nt], whi, wlo, yh[0][kt], yl[0][kt]);
            MFMA3(acc[1][nt], whi, wlo, yh[1][kt], yl[1][kt]);
        }
    }

    #pragma unroll
    for (int st = 0; st < 2; st++) {
        int arow = st ? r1 : r0;
        if (arow < M) {
            float sc = rowScale[arow];
            #pragma unroll
            for (int nt = 0; nt < 8; nt++) {
                int cbase = 32 * (nt >> 1) + 8 * g + 4 * (nt & 1);
                ushort4 o;
                o.x = (unsigned short)bfr16(acc[st][nt][0] * sc);
                o.y = (unsigned short)bfr16(acc[st][nt][1] * sc);
                o.z = (unsigned short)bfr16(acc[st][nt][2] * sc);
                o.w = (unsigned short)bfr16(acc[st][nt][3] * sc);
                *(ushort4*)(CoutHi + (size_t)arow * 128 + cbase) = o;
            }
        }
    }
}

// ---- fused predict MLP: gather xi/xj -> y1 -> y2 -> y3 -> dot -> out.
// 32 samples/wave (2 sets share weight fragments); LDS-staged weights with
// register-prefetch (issue next layer's global loads under current compute).
__global__ __launch_bounds__(512)
void mlp_k(const unsigned* __restrict__ X, const int* __restrict__ psrc, const int* __restrict__ pdst,
           const unsigned short* __restrict__ W1a, const unsigned short* __restrict__ W1b,
           const float* __restrict__ b1, const unsigned short* __restrict__ W2p,
           const float* __restrict__ b2, const unsigned short* __restrict__ W3p,
           const float* __restrict__ b3, const float* __restrict__ w4,
           const float* __restrict__ b4p, float* __restrict__ out, int M)
{
    __shared__ __align__(16) unsigned short smw[32768];   // 64 KB staging for active weights
    const int t = threadIdx.x, lane = t & 63, wave = t >> 6;
    const int base = blockIdx.x * 256 + wave * 32;
    const int s = lane & 15, g = lane >> 4, kg = g * 8;
    const int r0 = base + s, r1 = base + 16 + s;
    const int rc0 = (r0 < M) ? r0 : (M - 1);
    const int rc1 = (r1 < M) ? r1 : (M - 1);
    const int si0 = psrc[rc0], sj0 = pdst[rc0];
    const int si1 = psrc[rc1], sj1 = pdst[rc1];

    uint4 wreg[8];

    // ---- startup: stage W1a (unhidden, once) ----
    stage_load(wreg, W1a, t);
    stage_write(smw, wreg, t);
    __syncthreads();

    f32x4 acc1[2][8];
    #pragma unroll
    for (int st = 0; st < 2; st++)
        #pragma unroll
        for (int nt = 0; nt < 8; nt++) acc1[st][nt] = (f32x4){0.f, 0.f, 0.f, 0.f};

    // ---- phase 1a: xi @ W1a ; prefetch W1b ----
    stage_load(wreg, W1b, t);
    #pragma unroll
    for (int kt = 0; kt < 4; kt++) {
        bf16x8 x0h, x0l, x1h, x1l;
        frag_from_packed(X + (size_t)si0 * 128 + kt * 32 + kg, x0h, x0l);
        frag_from_packed(X + (size_t)si1 * 128 + kt * 32 + kg, x1h, x1l);
        #pragma unroll
        for (int nt = 0; nt < 8; nt++) {
            bf16x8 whi, wlo;
            wfrag_lds(smw, kt * 8 + nt, lane, whi, wlo);
            MFMA3(acc1[0][nt], whi, wlo, x0h, x0l);
            MFMA3(acc1[1][nt], whi, wlo, x1h, x1l);
        }
    }
    __syncthreads();                 // W1a reads done
    stage_write(smw, wreg, t);
    stage_load(wreg, W2p, t);        // prefetch W2 under phase 1b
    __syncthreads();                 // W1b visible

    // ---- phase 1b: xj @ W1b ----
    #pragma unroll
    for (int kt = 0; kt < 4; kt++) {
        bf16x8 x0h, x0l, x1h, x1l;
        frag_from_packed(X + (size_t)sj0 * 128 + kt * 32 + kg, x0h, x0l);
        frag_from_packed(X + (size_t)sj1 * 128 + kt * 32 + kg, x1h, x1l);
        #pragma unroll
        for (int nt = 0; nt < 8; nt++) {
            bf16x8 whi, wlo;
            wfrag_lds(smw, kt * 8 + nt, lane, whi, wlo);
            MFMA3(acc1[0][nt], whi, wlo, x0h, x0l);
            MFMA3(acc1[1][nt], whi, wlo, x1h, x1l);
        }
    }
    __syncthreads();                 // W1b reads done
    stage_write(smw, wreg, t);
    __syncthreads();                 // W2 visible

    // ---- layer 2 (no W3 prefetch here: acc1+acc2 peak; keep VGPR down) ----
    f32x4 acc2[2][8];
    #pragma unroll
    for (int st = 0; st < 2; st++)
        #pragma unroll
        for (int nt = 0; nt < 8; nt++) acc2[st][nt] = (f32x4){0.f, 0.f, 0.f, 0.f};
    #pragma unroll
    for (int kt = 0; kt < 4; kt++) {
        float4 bva = *(const float4*)(b1 + 32 * kt + 8 * g);
        float4 bvb = *(const float4*)(b1 + 32 * kt + 8 * g + 4);
        bf16x8 y0h, y0l, y1h, y1l;
        trans_frag(acc1[0], bva, bvb, kt, y0h, y0l);
        trans_frag(acc1[1], bva, bvb, kt, y1h, y1l);
        #pragma unroll
        for (int nt = 0; nt < 8; nt++) {
            bf16x8 whi, wlo;
            wfrag_lds(smw, kt * 8 + nt, lane, whi, wlo);
            MFMA3(acc2[0][nt], whi, wlo, y0h, y0l);
            MFMA3(acc2[1][nt], whi, wlo, y1h, y1l);
        }
    }
    __syncthreads();                 // W2 reads done
    stage_load(wreg, W3p, t);
    stage_write(smw, wreg, t);
    __syncthreads();                 // W3 visible

    // ---- layer 3 ----
    f32x4 acc3[2][8];
    #pragma unroll
    for (int st = 0; st < 2; st++)
        #pragma unroll
        for (int nt = 0; nt < 8; nt++) acc3[st][nt] = (f32x4){0.f, 0.f, 0.f, 0.f};
    #pragma unroll
    for (int kt = 0; kt < 4; kt++) {
        float4 bva = *(const float4*)(b2 + 32 * kt + 8 * g);
        float4 bvb = *(const float4*)(b2 + 32 * kt + 8 * g + 4);
        bf16x8 y0h, y0l, y1h, y1l;
        trans_frag(acc2[0], bva, bvb, kt, y0h, y0l);
        trans_frag(acc2[1], bva, bvb, kt, y1h, y1l);
        #pragma unroll
        for (int nt = 0; nt < 8; nt++) {
            bf16x8 whi, wlo;
            wfrag_lds(smw, kt * 8 + nt, lane, whi, wlo);
            MFMA3(acc3[0][nt], whi, wlo, y0h, y0l);
            MFMA3(acc3[1][nt], whi, wlo, y1h, y1l);
        }
    }

    // ---- final: out = relu( sum_c relu(y3[c]) * w4[c] + b4 ) ----
    float p0 = 0.f, p1 = 0.f;
    #pragma unroll
    for (int nt = 0; nt < 8; nt++) {
        int off = 32 * (nt >> 1) + 8 * g + 4 * (nt & 1);
        float4 b3v = *(const float4*)(b3 + off);
        float4 w4v = *(const float4*)(w4 + off);
        p0 += fmaxf(acc3[0][nt][0] + b3v.x, 0.f) * w4v.x;
        p0 += fmaxf(acc3[0][nt][1] + b3v.y, 0.f) * w4v.y;
        p0 += fmaxf(acc3[0][nt][2] + b3v.z, 0.f) * w4v.z;
        p0 += fmaxf(acc3[0][nt][3] + b3v.w, 0.f) * w4v.w;
        p1 += fmaxf(acc3[1][nt][0] + b3v.x, 0.f) * w4v.x;
        p1 += fmaxf(acc3[1][nt][1] + b3v.y, 0.f) * w4v.y;
        p1 += fmaxf(acc3[1][nt][2] + b3v.z, 0.f) * w4v.z;
        p1 += fmaxf(acc3[1][nt][3] + b3v.w, 0.f) * w4v.w;
    }
    p0 += __shfl_xor(p0, 16, 64);
    p0 += __shfl_xor(p0, 32, 64);
    p1 += __shfl_xor(p1, 16, 64);
    p1 += __shfl_xor(p1, 32, 64);
    if (g == 0) {
        float bb = b4p[0];
        if (r0 < M) out[r0] = fmaxf(p0 + bb, 0.f);
        if (r1 < M) out[r1] = fmaxf(p1 + bb, 0.f);
    }
}

extern "C" void kernel_launch(void* const* d_in, const int* in_sizes, int n_in,
                              void* d_out, int out_size, void* d_ws, size_t ws_size,
                              hipStream_t stream)
{
    const float* x   = (const float*)d_in[0];
    const int*   ei  = (const int*)d_in[2];
    const int*   pei = (const int*)d_in[3];
    const float* W1  = (const float*)d_in[4];
    const float* b1  = (const float*)d_in[5];
    const float* W2  = (const float*)d_in[6];
    const float* b2  = (const float*)d_in[7];
    // d_in[8..11] = edge_mlp weights: dead w.r.t. output, skipped
    const float* pW1 = (const float*)d_in[12];
    const float* pb1 = (const float*)d_in[13];
    const float* pW2 = (const float*)d_in[14];
    const float* pb2 = (const float*)d_in[15];
    const float* pW3 = (const float*)d_in[16];
    const float* pb3 = (const float*)d_in[17];
    const float* pW4 = (const float*)d_in[18];
    const float* pb4 = (const float*)d_in[19];

    const int N  = in_sizes[0] / 128;
    const int E  = in_sizes[2] / 2;
    const int EP = in_sizes[3] / 2;
    const int Npad = (N + 255) & ~255;

    float*    ws     = (float*)d_ws;
    float*    dinv   = ws;                                  // Npad
    unsigned* bufA   = (unsigned*)(ws + Npad);              // N*128 u32 region (hp uses half as bf16 plane)
    unsigned* bufB   = bufA + (size_t)N * 128;              // N*128 packed split-bf16
    int*      deg    = (int*)(bufB + (size_t)N * 128);      // Npad
    int*      rowptr = deg + Npad;                          // Npad
    int*      cursor = rowptr + Npad;                       // Npad
    int*      csr    = cursor + Npad;                       // E
    int*      bsum   = csr + E;                             // 512
    size_t wpOff = ((size_t)(bsum + 512) + 15) & ~(size_t)15;
    unsigned short* wp = (unsigned short*)wpOff;            // 6 x 32768 u16
    unsigned short* W1p  = wp;
    unsigned short* W2p  = wp + 32768;
    unsigned short* P1Ap = wp + 2 * 32768;
    unsigned short* P1Bp = wp + 3 * 32768;
    unsigned short* P2p  = wp + 4 * 32768;
    unsigned short* P3p  = wp + 5 * 32768;
    unsigned short* hpHi = (unsigned short*)bufA;           // bf16 hi-plane, N*128 u16
    float* out = (float*)d_out;

    const int* esrc = ei;
    const int* edst = ei + E;
    const int* psrc = pei;
    const int* pdst = pei + EP;

    const int nb = (N + 255) / 256;
    const int gN = (N + 255) / 256;
    const int gE = (E + 255) / 256;
    const int gT = (N + 255) / 256;     // 256 rows per block (2 sets/wave)
    const int gP = (EP + 255) / 256;
    const int gG = (N + 15) / 16;

    // ---- CSR build + dinv ----
    zero2_k<<<gN, 256, 0, stream>>>(deg, cursor, N);
    hist_k<<<gE, 256, 0, stream>>>(edst, deg, E);
    scan1_k<<<nb, 256, 0, stream>>>(deg, rowptr, bsum, dinv, N);
    scan2_k<<<1, 512, 0, stream>>>(bsum, nb);
    scan3_k<<<gN, 256, 0, stream>>>(rowptr, bsum, N);
    place_k<<<gE, 256, 0, stream>>>(esrc, edst, rowptr, cursor, csr, E);

    // ---- weight prep ----
    wprep6_k<<<dim3(64, 6), 256, 0, stream>>>(W1, W2, pW1, pW1 + 128 * 128, pW2, pW3, wp);

    // ---- layer 0: hp1 = dinv ⊙ (x@W1) [bf16 hi-plane]; x1r = relu(agg + b1) [packed] ----
    rowgemm_k<0><<<gT, 512, 0, stream>>>(x, W1p, dinv, hpHi, N);
    gather4_k<<<gG, 256, 0, stream>>>(hpHi, dinv, rowptr, deg, csr, b1, bufB, N);

    // ---- layer 1 ----
    rowgemm_k<1><<<gT, 512, 0, stream>>>(bufB, W2p, dinv, hpHi, N);
    gather4_k<<<gG, 256, 0, stream>>>(hpHi, dinv, rowptr, deg, csr, b2, bufB, N);

    // ---- fused predict MLP ----
    mlp_k<<<gP, 512, 0, stream>>>(bufB, psrc, pdst, P1Ap, P1Bp, pb1, P2p, pb2, P3p, pb3,
                                  pW4, pb4, out, EP);
}

// Round 10
// 273.792 us; speedup vs baseline: 1.0210x; 1.0210x over previous
//
#include <hip/hip_runtime.h>

typedef __attribute__((ext_vector_type(8))) short bf16x8;
typedef __attribute__((ext_vector_type(4))) float f32x4;
typedef __attribute__((ext_vector_type(16))) float f32x16;

// ---- split-bf16 helpers: value v ~ hi + lo, packed as (hi16<<16)|lo16 ----
__device__ __forceinline__ unsigned bfr16(float x) {            // RNE fp32->bf16 bits
    unsigned u = __float_as_uint(x);
    return (u + 0x7fffu + ((u >> 16) & 1u)) >> 16;
}
__device__ __forceinline__ unsigned pack_bf2(float v) {
    unsigned hr = bfr16(v);
    float lof = v - __uint_as_float(hr << 16);
    unsigned lr = bfr16(lof);
    return (hr << 16) | (lr & 0xffffu);
}
// bf16 pair decode (two ushorts in one u32)
__device__ __forceinline__ float lo16f(unsigned u) { return __uint_as_float(u << 16); }
__device__ __forceinline__ float hi16f(unsigned u) { return __uint_as_float(u & 0xffff0000u); }

union U8 { bf16x8 v; unsigned u[4]; };

// activation fragment from 8 consecutive packed u32
__device__ __forceinline__ void frag_from_packed(const unsigned* ap, bf16x8& hi, bf16x8& lo) {
    uint4 u0 = *(const uint4*)ap;
    uint4 u1 = *(const uint4*)(ap + 4);
    U8 H, L;
    H.u[0] = __builtin_amdgcn_perm(u0.y, u0.x, 0x07060302u);
    H.u[1] = __builtin_amdgcn_perm(u0.w, u0.z, 0x07060302u);
    H.u[2] = __builtin_amdgcn_perm(u1.y, u1.x, 0x07060302u);
    H.u[3] = __builtin_amdgcn_perm(u1.w, u1.z, 0x07060302u);
    L.u[0] = __builtin_amdgcn_perm(u0.y, u0.x, 0x05040100u);
    L.u[1] = __builtin_amdgcn_perm(u0.w, u0.z, 0x05040100u);
    L.u[2] = __builtin_amdgcn_perm(u1.y, u1.x, 0x05040100u);
    L.u[3] = __builtin_amdgcn_perm(u1.w, u1.z, 0x05040100u);
    hi = H.v; lo = L.v;
}

__device__ __forceinline__ void frag_from_f32(const float* fp, bf16x8& hi, bf16x8& lo) {
    float4 f0 = *(const float4*)fp;
    float4 f1 = *(const float4*)(fp + 4);
    float fv[8] = {f0.x, f0.y, f0.z, f0.w, f1.x, f1.y, f1.z, f1.w};
    U8 H, L;
    #pragma unroll
    for (int p = 0; p < 4; p++) {
        float a = fv[2 * p], b = fv[2 * p + 1];
        unsigned ra = bfr16(a), rb = bfr16(b);
        H.u[p] = ra | (rb << 16);
        float la = a - __uint_as_float(ra << 16);
        float lb = b - __uint_as_float(rb << 16);
        L.u[p] = bfr16(la) | (bfr16(lb) << 16);
    }
    hi = H.v; lo = L.v;
}

// stage one prepped weight matrix (64 KB) into LDS — 512-thread and 256-thread variants
__device__ __forceinline__ void stage_w512(unsigned short* sm, const unsigned short* Wp, int t) {
    const uint4* src = (const uint4*)Wp;
    uint4* dst = (uint4*)sm;
    #pragma unroll
    for (int p = 0; p < 8; p++) dst[t + p * 512] = src[t + p * 512];
}
__device__ __forceinline__ void stage_w256(unsigned short* sm, const unsigned short* Wp, int t) {
    const uint4* src = (const uint4*)Wp;
    uint4* dst = (uint4*)sm;
    #pragma unroll
    for (int p = 0; p < 16; p++) dst[t + p * 256] = src[t + p * 256];
}

// weight fragment pair from LDS (hi at 0, lo at +16384 u16)
__device__ __forceinline__ void wfrag_lds(const unsigned short* sm, int f, int lane,
                                          bf16x8& whi, bf16x8& wlo) {
    whi = *(const bf16x8*)(sm + f * 512 + lane * 8);
    wlo = *(const bf16x8*)(sm + 16384 + f * 512 + lane * 8);
}

#define MFMA3(accv, whi, wlo, yhi, ylo)                                              \
    accv = __builtin_amdgcn_mfma_f32_16x16x32_bf16(whi, yhi, accv, 0, 0, 0);         \
    accv = __builtin_amdgcn_mfma_f32_16x16x32_bf16(whi, ylo, accv, 0, 0, 0);         \
    accv = __builtin_amdgcn_mfma_f32_16x16x32_bf16(wlo, yhi, accv, 0, 0, 0);

#define MFMA3W(accv, whi, wlo, yhi, ylo)                                             \
    accv = __builtin_amdgcn_mfma_f32_32x32x16_bf16(whi, yhi, accv, 0, 0, 0);         \
    accv = __builtin_amdgcn_mfma_f32_32x32x16_bf16(whi, ylo, accv, 0, 0, 0);         \
    accv = __builtin_amdgcn_mfma_f32_32x32x16_bf16(wlo, yhi, accv, 0, 0, 0);

// ---- 16x16 path slot map (GCN layers): chan(nt, rho=4g+r) = 32*(nt>>1)+8*g+4*(nt&1)+r
// ---- 32x32 path slot map (MLP): D slot (n, reg, h=lane>>5) <-> true channel
//      c = kt*16 + h*8 + j  with kt = 2n + (reg>>3), j = reg&7
//      => next-layer B-frag(kt) = acc[kt>>1][(kt&1)*8 + j], j=0..7 (register relabel)

// 32x32 layer transition: y(kt) fragment from acc half + bias (+relu)
__device__ __forceinline__ void trans32(const f32x16& A, int sb, float4 bva, float4 bvb,
                                        bf16x8& yh, bf16x8& yl) {
    float v0 = fmaxf(A[sb + 0] + bva.x, 0.f);
    float v1 = fmaxf(A[sb + 1] + bva.y, 0.f);
    float v2 = fmaxf(A[sb + 2] + bva.z, 0.f);
    float v3 = fmaxf(A[sb + 3] + bva.w, 0.f);
    float v4 = fmaxf(A[sb + 4] + bvb.x, 0.f);
    float v5 = fmaxf(A[sb + 5] + bvb.y, 0.f);
    float v6 = fmaxf(A[sb + 6] + bvb.z, 0.f);
    float v7 = fmaxf(A[sb + 7] + bvb.w, 0.f);
    U8 H, L;
    unsigned ra, rb;
    ra = bfr16(v0); rb = bfr16(v1);
    H.u[0] = ra | (rb << 16);
    L.u[0] = bfr16(v0 - __uint_as_float(ra << 16)) | (bfr16(v1 - __uint_as_float(rb << 16)) << 16);
    ra = bfr16(v2); rb = bfr16(v3);
    H.u[1] = ra | (rb << 16);
    L.u[1] = bfr16(v2 - __uint_as_float(ra << 16)) | (bfr16(v3 - __uint_as_float(rb << 16)) << 16);
    ra = bfr16(v4); rb = bfr16(v5);
    H.u[2] = ra | (rb << 16);
    L.u[2] = bfr16(v4 - __uint_as_float(ra << 16)) | (bfr16(v5 - __uint_as_float(rb << 16)) << 16);
    ra = bfr16(v6); rb = bfr16(v7);
    H.u[3] = ra | (rb << 16);
    L.u[3] = bfr16(v6 - __uint_as_float(ra << 16)) | (bfr16(v7 - __uint_as_float(rb << 16)) << 16);
    yh = H.v; yl = L.v;
}

// ---------------- CSR build ----------------

__global__ void zero2_k(int* __restrict__ a, int* __restrict__ b, int n) {
    int i = blockIdx.x * blockDim.x + threadIdx.x;
    if (i < n) { a[i] = 0; b[i] = 0; }
}

__global__ void hist_k(const int* __restrict__ dst, int* __restrict__ deg, int E) {
    int e = blockIdx.x * blockDim.x + threadIdx.x;
    if (e < E) atomicAdd(&deg[dst[e]], 1);
}

__global__ void scan1_k(const int* __restrict__ deg, int* __restrict__ rowptr,
                        int* __restrict__ bsum, float* __restrict__ dinv, int n) {
    __shared__ int s[256];
    int tid = threadIdx.x;
    int i = blockIdx.x * 256 + tid;
    int v = (i < n) ? deg[i] : 0;
    s[tid] = v;
    __syncthreads();
    #pragma unroll
    for (int off = 1; off < 256; off <<= 1) {
        int t = (tid >= off) ? s[tid - off] : 0;
        __syncthreads();
        s[tid] += t;
        __syncthreads();
    }
    if (i < n) {
        rowptr[i] = s[tid] - v;
        dinv[i] = rsqrtf((float)(v + 1));
    }
    if (tid == 255) bsum[blockIdx.x] = s[255];
}

__global__ void scan2_k(int* __restrict__ bsum, int nb) {
    __shared__ int s[512];
    int tid = threadIdx.x;
    int v = (tid < nb) ? bsum[tid] : 0;
    s[tid] = v;
    __syncthreads();
    #pragma unroll
    for (int off = 1; off < 512; off <<= 1) {
        int t = (tid >= off) ? s[tid - off] : 0;
        __syncthreads();
        s[tid] += t;
        __syncthreads();
    }
    if (tid < nb) bsum[tid] = s[tid] - v;
}

__global__ void scan3_k(int* __restrict__ rowptr, const int* __restrict__ bsum, int n) {
    int i = blockIdx.x * blockDim.x + threadIdx.x;
    if (i < n) rowptr[i] += bsum[i >> 8];
}

__global__ void place_k(const int* __restrict__ src, const int* __restrict__ dst,
                        const int* __restrict__ rowptr, int* __restrict__ cursor,
                        int* __restrict__ csr, int E) {
    int e = blockIdx.x * blockDim.x + threadIdx.x;
    if (e < E) {
        int d = dst[e];
        int pos = rowptr[d] + atomicAdd(&cursor[d], 1);
        csr[pos] = src[e];
    }
}

// ---- weight prep. y=0,1 -> 16x16 A-frag format (GCN). y=2..5 -> 32x32 A-frag format (MLP).
__global__ void wprep6_k(const float* __restrict__ s0, const float* __restrict__ s1,
                         const float* __restrict__ s2, const float* __restrict__ s3,
                         const float* __restrict__ s4, const float* __restrict__ s5,
                         unsigned short* __restrict__ dstBase) {
    const float* W;
    switch (blockIdx.y) {
        case 0: W = s0; break; case 1: W = s1; break; case 2: W = s2; break;
        case 3: W = s3; break; case 4: W = s4; break; default: W = s5; break;
    }
    unsigned short* out = dstBase + (size_t)blockIdx.y * 32768;
    int idx = blockIdx.x * 256 + threadIdx.x;
    if (idx >= 16384) return;
    int k = idx >> 7, c = idx & 127;
    float v = W[k * 128 + c];
    unsigned hr = bfr16(v);
    float lof = v - __uint_as_float(hr << 16);
    unsigned lr = bfr16(lof);
    int pos;
    if (blockIdx.y < 2) {
        // 16x16x32: frag f = kt*8+nt ; lane = ((k>>3)&3)<<4 | rho ; elem j = k&7
        int kt = k >> 5, gk = (k >> 3) & 3, j = k & 7;
        int nt = ((c >> 5) << 1) | ((c >> 2) & 1);
        int rho = (((c >> 3) & 3) << 2) | (c & 3);
        int lane = (gk << 4) | rho;
        pos = (kt * 8 + nt) * 512 + lane * 8 + j;
    } else {
        // 32x32x16: c -> (ktc, hc, jc); slot reg = ((ktc&1)<<3)|jc, n = ktc>>1;
        // A-row m = (reg&3)+8*(reg>>2)+4*hc ; lane = ((k>>3)&1)<<5 | m ; frag f = (k>>4)*4+n
        int kk = k >> 4, gk = (k >> 3) & 1, jj = k & 7;
        int ktc = c >> 4, hc = (c >> 3) & 1, jc = c & 7;
        int n = ktc >> 1;
        int reg = ((ktc & 1) << 3) | jc;
        int m = (reg & 3) + 8 * (reg >> 2) + 4 * hc;
        int lane = (gk << 5) | m;
        pos = (kk * 4 + n) * 512 + lane * 8 + jj;
    }
    out[pos] = (unsigned short)hr;
    out[16384 + pos] = (unsigned short)lr;
}

// ---- gather aggregate: out[i] = relu(bias + dinv[i]*(hp[i] + sum_in hp[s])).
// hp = bf16 hi-plane (2 B/chan). 4 nodes/wave, 16 lanes x 8 chans; 8-deep unroll.
__global__ __launch_bounds__(256)
void gather4_k(const unsigned short* __restrict__ hp, const float* __restrict__ dinv,
               const int* __restrict__ rowptr, const int* __restrict__ deg,
               const int* __restrict__ csr, const float* __restrict__ bias,
               unsigned* __restrict__ out, int N)
{
    int tid = threadIdx.x;
    int lane = tid & 63;
    int grp = lane >> 4, cl = lane & 15;
    int i = blockIdx.x * 16 + (tid >> 6) * 4 + grp;
    if (i >= N) return;
    int c8 = cl * 8;
    uint4 p = *(const uint4*)(hp + (size_t)i * 128 + c8);
    float a0 = lo16f(p.x), a1 = hi16f(p.x), a2 = lo16f(p.y), a3 = hi16f(p.y);
    float a4 = lo16f(p.z), a5 = hi16f(p.z), a6 = lo16f(p.w), a7 = hi16f(p.w);
    int beg = rowptr[i], dg = deg[i];
    int j = 0;
    for (; j + 7 < dg; j += 8) {
        uint4 q[8];
        #pragma unroll
        for (int u = 0; u < 8; u++) {
            int su = csr[beg + j + u];
            q[u] = *(const uint4*)(hp + (size_t)su * 128 + c8);
        }
        #pragma unroll
        for (int u = 0; u < 8; u++) {
            a0 += lo16f(q[u].x); a1 += hi16f(q[u].x);
            a2 += lo16f(q[u].y); a3 += hi16f(q[u].y);
            a4 += lo16f(q[u].z); a5 += hi16f(q[u].z);
            a6 += lo16f(q[u].w); a7 += hi16f(q[u].w);
        }
    }
    for (; j + 3 < dg; j += 4) {
        uint4 q[4];
        #pragma unroll
        for (int u = 0; u < 4; u++) {
            int su = csr[beg + j + u];
            q[u] = *(const uint4*)(hp + (size_t)su * 128 + c8);
        }
        #pragma unroll
        for (int u = 0; u < 4; u++) {
            a0 += lo16f(q[u].x); a1 += hi16f(q[u].x);
            a2 += lo16f(q[u].y); a3 += hi16f(q[u].y);
            a4 += lo16f(q[u].z); a5 += hi16f(q[u].z);
            a6 += lo16f(q[u].w); a7 += hi16f(q[u].w);
        }
    }
    for (; j < dg; j++) {
        int s0 = csr[beg + j];
        uint4 q0 = *(const uint4*)(hp + (size_t)s0 * 128 + c8);
        a0 += lo16f(q0.x); a1 += hi16f(q0.x); a2 += lo16f(q0.y); a3 += hi16f(q0.y);
        a4 += lo16f(q0.z); a5 += hi16f(q0.z); a6 += lo16f(q0.w); a7 += hi16f(q0.w);
    }
    float di = dinv[i];
    float4 bv0 = *(const float4*)(bias + c8);
    float4 bv1 = *(const float4*)(bias + c8 + 4);
    uint4 o0, o1;
    o0.x = pack_bf2(fmaxf(bv0.x + di * a0, 0.f));
    o0.y = pack_bf2(fmaxf(bv0.y + di * a1, 0.f));
    o0.z = pack_bf2(fmaxf(bv0.z + di * a2, 0.f));
    o0.w = pack_bf2(fmaxf(bv0.w + di * a3, 0.f));
    o1.x = pack_bf2(fmaxf(bv1.x + di * a4, 0.f));
    o1.y = pack_bf2(fmaxf(bv1.y + di * a5, 0.f));
    o1.z = pack_bf2(fmaxf(bv1.z + di * a6, 0.f));
    o1.w = pack_bf2(fmaxf(bv1.w + di * a7, 0.f));
    *(uint4*)(out + (size_t)i * 128 + c8) = o0;
    *(uint4*)(out + (size_t)i * 128 + c8 + 4) = o1;
}

// ---- layer GEMM (16x16 path, round-8 verified): Chp = dinv ⊙ (A @ W) as bf16 hi-plane.
template<int AMODE>   // 0: A fp32 ; 1: A packed split-bf16
__global__ __launch_bounds__(512)
void rowgemm_k(const void* __restrict__ Asrc, const unsigned short* __restrict__ Wp,
               const float* __restrict__ rowScale, unsigned short* __restrict__ CoutHi, int M)
{
    __shared__ __align__(16) unsigned short smw[32768];
    const int t = threadIdx.x, lane = t & 63, wave = t >> 6;
    const int base = blockIdx.x * 128 + wave * 16;
    const int s = lane & 15, g = lane >> 4, kg = g * 8;
    const int arow = base + s;
    const int rowc = (arow < M) ? arow : (M - 1);

    stage_w512(smw, Wp, t);

    bf16x8 yh[4], yl[4];
    #pragma unroll
    for (int kt = 0; kt < 4; kt++) {
        if (AMODE == 1)
            frag_from_packed((const unsigned*)Asrc + (size_t)rowc * 128 + kt * 32 + kg, yh[kt], yl[kt]);
        else
            frag_from_f32((const float*)Asrc + (size_t)rowc * 128 + kt * 32 + kg, yh[kt], yl[kt]);
    }
    __syncthreads();

    f32x4 acc[8];
    #pragma unroll
    for (int nt = 0; nt < 8; nt++) acc[nt] = (f32x4){0.f, 0.f, 0.f, 0.f};

    #pragma unroll
    for (int kt = 0; kt < 4; kt++) {
        #pragma unroll
        for (int nt = 0; nt < 8; nt++) {
            bf16x8 whi, wlo;
            wfrag_lds(smw, kt * 8 + nt, lane, whi, wlo);
            MFMA3(acc[nt], whi, wlo, yh[kt], yl[kt]);
        }
    }

    if (arow < M) {
        float sc = rowScale[arow];
        #pragma unroll
        for (int nt = 0; nt < 8; nt++) {
            int cbase = 32 * (nt >> 1) + 8 * g + 4 * (nt & 1);
            ushort4 o;
            o.x = (unsigned short)bfr16(acc[nt][0] * sc);
            o.y = (unsigned short)bfr16(acc[nt][1] * sc);
            o.z = (unsigned short)bfr16(acc[nt][2] * sc);
            o.w = (unsigned short)bfr16(acc[nt][3] * sc);
            *(ushort4*)(CoutHi + (size_t)arow * 128 + cbase) = o;
        }
    }
}

// ---- fused predict MLP (32x32x16 path): gather xi/xj -> y1 -> y2 -> y3 -> dot -> out.
// 32 samples/wave, 4 waves (128 samples/block). Weights staged in LDS per layer.
__global__ __launch_bounds__(256)
void mlp_k(const unsigned* __restrict__ X, const int* __restrict__ psrc, const int* __restrict__ pdst,
           const unsigned short* __restrict__ W1a, const unsigned short* __restrict__ W1b,
           const float* __restrict__ b1, const unsigned short* __restrict__ W2p,
           const float* __restrict__ b2, const unsigned short* __restrict__ W3p,
           const float* __restrict__ b3, const float* __restrict__ w4,
           const float* __restrict__ b4p, float* __restrict__ out, int M)
{
    __shared__ __align__(16) unsigned short smw[32768];
    const int t = threadIdx.x, lane = t & 63, wave = t >> 6;
    const int base = blockIdx.x * 128 + wave * 32;
    const int s = lane & 31, h8 = (lane >> 5) * 8;
    const int arow = base + s;
    const int rowc = (arow < M) ? arow : (M - 1);
    const int si = psrc[rowc], sj = pdst[rowc];

    f32x16 acc1[4];
    #pragma unroll
    for (int nt = 0; nt < 4; nt++)
        #pragma unroll
        for (int q = 0; q < 16; q++) acc1[nt][q] = 0.f;

    // ---- phase 1a: xi @ W1a ----
    stage_w256(smw, W1a, t);
    __syncthreads();
    #pragma unroll
    for (int kt = 0; kt < 8; kt++) {
        bf16x8 xh, xl;
        frag_from_packed(X + (size_t)si * 128 + kt * 16 + h8, xh, xl);
        #pragma unroll
        for (int nt = 0; nt < 4; nt++) {
            bf16x8 whi, wlo;
            wfrag_lds(smw, kt * 4 + nt, lane, whi, wlo);
            MFMA3W(acc1[nt], whi, wlo, xh, xl);
        }
    }
    __syncthreads();

    // ---- phase 1b: xj @ W1b ----
    stage_w256(smw, W1b, t);
    __syncthreads();
    #pragma unroll
    for (int kt = 0; kt < 8; kt++) {
        bf16x8 xh, xl;
        frag_from_packed(X + (size_t)sj * 128 + kt * 16 + h8, xh, xl);
        #pragma unroll
        for (int nt = 0; nt < 4; nt++) {
            bf16x8 whi, wlo;
            wfrag_lds(smw, kt * 4 + nt, lane, whi, wlo);
            MFMA3W(acc1[nt], whi, wlo, xh, xl);
        }
    }
    __syncthreads();

    // ---- layer 2: y = relu(acc1 + b1) @ W2 (register relabel transition) ----
    stage_w256(smw, W2p, t);
    __syncthreads();
    f32x16 acc2[4];
    #pragma unroll
    for (int nt = 0; nt < 4; nt++)
        #pragma unroll
        for (int q = 0; q < 16; q++) acc2[nt][q] = 0.f;
    #pragma unroll
    for (int kt = 0; kt < 8; kt++) {
        float4 bva = *(const float4*)(b1 + kt * 16 + h8);
        float4 bvb = *(const float4*)(b1 + kt * 16 + h8 + 4);
        bf16x8 yh, yl;
        trans32(acc1[kt >> 1], (kt & 1) * 8, bva, bvb, yh, yl);
        #pragma unroll
        for (int nt = 0; nt < 4; nt++) {
            bf16x8 whi, wlo;
            wfrag_lds(smw, kt * 4 + nt, lane, whi, wlo);
            MFMA3W(acc2[nt], whi, wlo, yh, yl);
        }
    }
    __syncthreads();

    // ---- layer 3 ----
    stage_w256(smw, W3p, t);
    __syncthreads();
    f32x16 acc3[4];
    #pragma unroll
    for (int nt = 0; nt < 4; nt++)
        #pragma unroll
        for (int q = 0; q < 16; q++) acc3[nt][q] = 0.f;
    #pragma unroll
    for (int kt = 0; kt < 8; kt++) {
        float4 bva = *(const float4*)(b2 + kt * 16 + h8);
        float4 bvb = *(const float4*)(b2 + kt * 16 + h8 + 4);
        bf16x8 yh, yl;
        trans32(acc2[kt >> 1], (kt & 1) * 8, bva, bvb, yh, yl);
        #pragma unroll
        for (int nt = 0; nt < 4; nt++) {
            bf16x8 whi, wlo;
            wfrag_lds(smw, kt * 4 + nt, lane, whi, wlo);
            MFMA3W(acc3[nt], whi, wlo, yh, yl);
        }
    }

    // ---- final: out = relu( sum_c relu(y3[c]) * w4[c] + b4 ) ----
    // slot c: regs 0..7 -> c = 32n + h8 + j ; regs 8..15 -> c = 32n + 16 + h8 + j
    float p = 0.f;
    #pragma unroll
    for (int nt = 0; nt < 4; nt++) {
        int c1 = 32 * nt + h8;
        int c2 = 32 * nt + 16 + h8;
        float4 b3a = *(const float4*)(b3 + c1);
        float4 b3b = *(const float4*)(b3 + c1 + 4);
        float4 b3c = *(const float4*)(b3 + c2);
        float4 b3d = *(const float4*)(b3 + c2 + 4);
        float4 w4a = *(const float4*)(w4 + c1);
        float4 w4b = *(const float4*)(w4 + c1 + 4);
        float4 w4c = *(const float4*)(w4 + c2);
        float4 w4d = *(const float4*)(w4 + c2 + 4);
        p += fmaxf(acc3[nt][0]  + b3a.x, 0.f) * w4a.x;
        p += fmaxf(acc3[nt][1]  + b3a.y, 0.f) * w4a.y;
        p += fmaxf(acc3[nt][2]  + b3a.z, 0.f) * w4a.z;
        p += fmaxf(acc3[nt][3]  + b3a.w, 0.f) * w4a.w;
        p += fmaxf(acc3[nt][4]  + b3b.x, 0.f) * w4b.x;
        p += fmaxf(acc3[nt][5]  + b3b.y, 0.f) * w4b.y;
        p += fmaxf(acc3[nt][6]  + b3b.z, 0.f) * w4b.z;
        p += fmaxf(acc3[nt][7]  + b3b.w, 0.f) * w4b.w;
        p += fmaxf(acc3[nt][8]  + b3c.x, 0.f) * w4c.x;
        p += fmaxf(acc3[nt][9]  + b3c.y, 0.f) * w4c.y;
        p += fmaxf(acc3[nt][10] + b3c.z, 0.f) * w4c.z;
        p += fmaxf(acc3[nt][11] + b3c.w, 0.f) * w4c.w;
        p += fmaxf(acc3[nt][12] + b3d.x, 0.f) * w4d.x;
        p += fmaxf(acc3[nt][13] + b3d.y, 0.f) * w4d.y;
        p += fmaxf(acc3[nt][14] + b3d.z, 0.f) * w4d.z;
        p += fmaxf(acc3[nt][15] + b3d.w, 0.f) * w4d.w;
    }
    p += __shfl_xor(p, 32, 64);
    if (lane < 32 && arow < M) out[arow] = fmaxf(p + b4p[0], 0.f);
}

extern "C" void kernel_launch(void* const* d_in, const int* in_sizes, int n_in,
                              void* d_out, int out_size, void* d_ws, size_t ws_size,
                              hipStream_t stream)
{
    const float* x   = (const float*)d_in[0];
    const int*   ei  = (const int*)d_in[2];
    const int*   pei = (const int*)d_in[3];
    const float* W1  = (const float*)d_in[4];
    const float* b1  = (const float*)d_in[5];
    const float* W2  = (const float*)d_in[6];
    const float* b2  = (const float*)d_in[7];
    // d_in[8..11] = edge_mlp weights: dead w.r.t. output, skipped
    const float* pW1 = (const float*)d_in[12];
    const float* pb1 = (const float*)d_in[13];
    const float* pW2 = (const float*)d_in[14];
    const float* pb2 = (const float*)d_in[15];
    const float* pW3 = (const float*)d_in[16];
    const float* pb3 = (const float*)d_in[17];
    const float* pW4 = (const float*)d_in[18];
    const float* pb4 = (const float*)d_in[19];

    const int N  = in_sizes[0] / 128;
    const int E  = in_sizes[2] / 2;
    const int EP = in_sizes[3] / 2;
    const int Npad = (N + 255) & ~255;

    float*    ws     = (float*)d_ws;
    float*    dinv   = ws;                                  // Npad
    unsigned* bufA   = (unsigned*)(ws + Npad);              // N*128 u32 (hp hi-plane uses half)
    unsigned* bufB   = bufA + (size_t)N * 128;              // N*128 packed split-bf16
    int*      deg    = (int*)(bufB + (size_t)N * 128);      // Npad
    int*      rowptr = deg + Npad;                          // Npad
    int*      cursor = rowptr + Npad;                       // Npad
    int*      csr    = cursor + Npad;                       // E
    int*      bsum   = csr + E;                             // 512
    size_t wpOff = ((size_t)(bsum + 512) + 15) & ~(size_t)15;
    unsigned short* wp = (unsigned short*)wpOff;            // 6 x 32768 u16
    unsigned short* W1p  = wp;
    unsigned short* W2p  = wp + 32768;
    unsigned short* P1Ap = wp + 2 * 32768;
    unsigned short* P1Bp = wp + 3 * 32768;
    unsigned short* P2p  = wp + 4 * 32768;
    unsigned short* P3p  = wp + 5 * 32768;
    unsigned short* hpHi = (unsigned short*)bufA;           // bf16 hi-plane, N*128 u16
    float* out = (float*)d_out;

    const int* esrc = ei;
    const int* edst = ei + E;
    const int* psrc = pei;
    const int* pdst = pei + EP;

    const int nb = (N + 255) / 256;
    const int gN = (N + 255) / 256;
    const int gE = (E + 255) / 256;
    const int gT = (N + 127) / 128;
    const int gP = (EP + 127) / 128;
    const int gG = (N + 15) / 16;

    // ---- CSR build + dinv ----
    zero2_k<<<gN, 256, 0, stream>>>(deg, cursor, N);
    hist_k<<<gE, 256, 0, stream>>>(edst, deg, E);
    scan1_k<<<nb, 256, 0, stream>>>(deg, rowptr, bsum, dinv, N);
    scan2_k<<<1, 512, 0, stream>>>(bsum, nb);
    scan3_k<<<gN, 256, 0, stream>>>(rowptr, bsum, N);
    place_k<<<gE, 256, 0, stream>>>(esrc, edst, rowptr, cursor, csr, E);

    // ---- weight prep (dual format) ----
    wprep6_k<<<dim3(64, 6), 256, 0, stream>>>(W1, W2, pW1, pW1 + 128 * 128, pW2, pW3, wp);

    // ---- layer 0: hp1 = dinv ⊙ (x@W1) [bf16 hi-plane]; x1r = relu(agg + b1) [packed] ----
    rowgemm_k<0><<<gT, 512, 0, stream>>>(x, W1p, dinv, hpHi, N);
    gather4_k<<<gG, 256, 0, stream>>>(hpHi, dinv, rowptr, deg, csr, b1, bufB, N);

    // ---- layer 1 ----
    rowgemm_k<1><<<gT, 512, 0, stream>>>(bufB, W2p, dinv, hpHi, N);
    gather4_k<<<gG, 256, 0, stream>>>(hpHi, dinv, rowptr, deg, csr, b2, bufB, N);

    // ---- fused predict MLP (32x32 path) ----
    mlp_k<<<gP, 256, 0, stream>>>(bufB, psrc, pdst, P1Ap, P1Bp, pb1, P2p, pb2, P3p, pb3,
                                  pW4, pb4, out, EP);
}

// Round 11
// 248.829 us; speedup vs baseline: 1.1234x; 1.1003x over previous
//
#include <hip/hip_runtime.h>

typedef __attribute__((ext_vector_type(8))) short bf16x8;
typedef __attribute__((ext_vector_type(4))) float f32x4;
typedef __attribute__((ext_vector_type(16))) float f32x16;

// ---- split-bf16 helpers: value v ~ hi + lo, packed as (hi16<<16)|lo16 ----
__device__ __forceinline__ unsigned bfr16(float x) {            // RNE fp32->bf16 bits
    unsigned u = __float_as_uint(x);
    return (u + 0x7fffu + ((u >> 16) & 1u)) >> 16;
}
__device__ __forceinline__ unsigned pack_bf2(float v) {
    unsigned hr = bfr16(v);
    float lof = v - __uint_as_float(hr << 16);
    unsigned lr = bfr16(lof);
    return (hr << 16) | (lr & 0xffffu);
}
// bf16 pair decode (two ushorts in one u32)
__device__ __forceinline__ float lo16f(unsigned u) { return __uint_as_float(u << 16); }
__device__ __forceinline__ float hi16f(unsigned u) { return __uint_as_float(u & 0xffff0000u); }

union U8 { bf16x8 v; unsigned u[4]; };

// activation fragment from 8 consecutive packed u32
__device__ __forceinline__ void frag_from_packed(const unsigned* ap, bf16x8& hi, bf16x8& lo) {
    uint4 u0 = *(const uint4*)ap;
    uint4 u1 = *(const uint4*)(ap + 4);
    U8 H, L;
    H.u[0] = __builtin_amdgcn_perm(u0.y, u0.x, 0x07060302u);
    H.u[1] = __builtin_amdgcn_perm(u0.w, u0.z, 0x07060302u);
    H.u[2] = __builtin_amdgcn_perm(u1.y, u1.x, 0x07060302u);
    H.u[3] = __builtin_amdgcn_perm(u1.w, u1.z, 0x07060302u);
    L.u[0] = __builtin_amdgcn_perm(u0.y, u0.x, 0x05040100u);
    L.u[1] = __builtin_amdgcn_perm(u0.w, u0.z, 0x05040100u);
    L.u[2] = __builtin_amdgcn_perm(u1.y, u1.x, 0x05040100u);
    L.u[3] = __builtin_amdgcn_perm(u1.w, u1.z, 0x05040100u);
    hi = H.v; lo = L.v;
}

__device__ __forceinline__ void frag_from_f32(const float* fp, bf16x8& hi, bf16x8& lo) {
    float4 f0 = *(const float4*)fp;
    float4 f1 = *(const float4*)(fp + 4);
    float fv[8] = {f0.x, f0.y, f0.z, f0.w, f1.x, f1.y, f1.z, f1.w};
    U8 H, L;
    #pragma unroll
    for (int p = 0; p < 4; p++) {
        float a = fv[2 * p], b = fv[2 * p + 1];
        unsigned ra = bfr16(a), rb = bfr16(b);
        H.u[p] = ra | (rb << 16);
        float la = a - __uint_as_float(ra << 16);
        float lb = b - __uint_as_float(rb << 16);
        L.u[p] = bfr16(la) | (bfr16(lb) << 16);
    }
    hi = H.v; lo = L.v;
}

// stage one prepped weight matrix (64 KB) into LDS with 512 threads
__device__ __forceinline__ void stage_w512(unsigned short* sm, const unsigned short* Wp, int t) {
    const uint4* src = (const uint4*)Wp;
    uint4* dst = (uint4*)sm;
    #pragma unroll
    for (int p = 0; p < 8; p++) dst[t + p * 512] = src[t + p * 512];
}

// weight fragment pair from LDS (hi at 0, lo at +16384 u16)
__device__ __forceinline__ void wfrag_lds(const unsigned short* sm, int f, int lane,
                                          bf16x8& whi, bf16x8& wlo) {
    whi = *(const bf16x8*)(sm + f * 512 + lane * 8);
    wlo = *(const bf16x8*)(sm + 16384 + f * 512 + lane * 8);
}

#define MFMA3(accv, whi, wlo, yhi, ylo)                                              \
    accv = __builtin_amdgcn_mfma_f32_16x16x32_bf16(whi, yhi, accv, 0, 0, 0);         \
    accv = __builtin_amdgcn_mfma_f32_16x16x32_bf16(whi, ylo, accv, 0, 0, 0);         \
    accv = __builtin_amdgcn_mfma_f32_16x16x32_bf16(wlo, yhi, accv, 0, 0, 0);

#define MFMA3W(accv, whi, wlo, yhi, ylo)                                             \
    accv = __builtin_amdgcn_mfma_f32_32x32x16_bf16(whi, yhi, accv, 0, 0, 0);         \
    accv = __builtin_amdgcn_mfma_f32_32x32x16_bf16(whi, ylo, accv, 0, 0, 0);         \
    accv = __builtin_amdgcn_mfma_f32_32x32x16_bf16(wlo, yhi, accv, 0, 0, 0);

// ---- 16x16 path slot map (GCN layers): chan(nt, rho=4g+r) = 32*(nt>>1)+8*g+4*(nt&1)+r
// ---- 32x32 path slot map (MLP): D slot (n, reg, h=lane>>5) <-> true channel
//      c = kt*16 + h*8 + j  with kt = 2n + (reg>>3), j = reg&7
//      => next-layer B-frag(kt) = acc[kt>>1][(kt&1)*8 + j], j=0..7 (register relabel)

// 32x32 layer transition: y(kt) fragment from acc half + bias (+relu)
__device__ __forceinline__ void trans32(const f32x16& A, int sb, float4 bva, float4 bvb,
                                        bf16x8& yh, bf16x8& yl) {
    float v0 = fmaxf(A[sb + 0] + bva.x, 0.f);
    float v1 = fmaxf(A[sb + 1] + bva.y, 0.f);
    float v2 = fmaxf(A[sb + 2] + bva.z, 0.f);
    float v3 = fmaxf(A[sb + 3] + bva.w, 0.f);
    float v4 = fmaxf(A[sb + 4] + bvb.x, 0.f);
    float v5 = fmaxf(A[sb + 5] + bvb.y, 0.f);
    float v6 = fmaxf(A[sb + 6] + bvb.z, 0.f);
    float v7 = fmaxf(A[sb + 7] + bvb.w, 0.f);
    U8 H, L;
    unsigned ra, rb;
    ra = bfr16(v0); rb = bfr16(v1);
    H.u[0] = ra | (rb << 16);
    L.u[0] = bfr16(v0 - __uint_as_float(ra << 16)) | (bfr16(v1 - __uint_as_float(rb << 16)) << 16);
    ra = bfr16(v2); rb = bfr16(v3);
    H.u[1] = ra | (rb << 16);
    L.u[1] = bfr16(v2 - __uint_as_float(ra << 16)) | (bfr16(v3 - __uint_as_float(rb << 16)) << 16);
    ra = bfr16(v4); rb = bfr16(v5);
    H.u[2] = ra | (rb << 16);
    L.u[2] = bfr16(v4 - __uint_as_float(ra << 16)) | (bfr16(v5 - __uint_as_float(rb << 16)) << 16);
    ra = bfr16(v6); rb = bfr16(v7);
    H.u[3] = ra | (rb << 16);
    L.u[3] = bfr16(v6 - __uint_as_float(ra << 16)) | (bfr16(v7 - __uint_as_float(rb << 16)) << 16);
    yh = H.v; yl = L.v;
}

// ---------------- CSR build ----------------

__global__ void zero2_k(int* __restrict__ a, int* __restrict__ b, int n) {
    int i = blockIdx.x * blockDim.x + threadIdx.x;
    if (i < n) { a[i] = 0; b[i] = 0; }
}

__global__ void hist_k(const int* __restrict__ dst, int* __restrict__ deg, int E) {
    int e = blockIdx.x * blockDim.x + threadIdx.x;
    if (e < E) atomicAdd(&deg[dst[e]], 1);
}

__global__ void scan1_k(const int* __restrict__ deg, int* __restrict__ rowptr,
                        int* __restrict__ bsum, float* __restrict__ dinv, int n) {
    __shared__ int s[256];
    int tid = threadIdx.x;
    int i = blockIdx.x * 256 + tid;
    int v = (i < n) ? deg[i] : 0;
    s[tid] = v;
    __syncthreads();
    #pragma unroll
    for (int off = 1; off < 256; off <<= 1) {
        int t = (tid >= off) ? s[tid - off] : 0;
        __syncthreads();
        s[tid] += t;
        __syncthreads();
    }
    if (i < n) {
        rowptr[i] = s[tid] - v;
        dinv[i] = rsqrtf((float)(v + 1));
    }
    if (tid == 255) bsum[blockIdx.x] = s[255];
}

__global__ void scan2_k(int* __restrict__ bsum, int nb) {
    __shared__ int s[512];
    int tid = threadIdx.x;
    int v = (tid < nb) ? bsum[tid] : 0;
    s[tid] = v;
    __syncthreads();
    #pragma unroll
    for (int off = 1; off < 512; off <<= 1) {
        int t = (tid >= off) ? s[tid - off] : 0;
        __syncthreads();
        s[tid] += t;
        __syncthreads();
    }
    if (tid < nb) bsum[tid] = s[tid] - v;
}

__global__ void scan3_k(int* __restrict__ rowptr, const int* __restrict__ bsum, int n) {
    int i = blockIdx.x * blockDim.x + threadIdx.x;
    if (i < n) rowptr[i] += bsum[i >> 8];
}

__global__ void place_k(const int* __restrict__ src, const int* __restrict__ dst,
                        const int* __restrict__ rowptr, int* __restrict__ cursor,
                        int* __restrict__ csr, int E) {
    int e = blockIdx.x * blockDim.x + threadIdx.x;
    if (e < E) {
        int d = dst[e];
        int pos = rowptr[d] + atomicAdd(&cursor[d], 1);
        csr[pos] = src[e];
    }
}

// ---- weight prep. y=0,1 -> 16x16 A-frag format (GCN). y=2..5 -> 32x32 A-frag format (MLP).
__global__ void wprep6_k(const float* __restrict__ s0, const float* __restrict__ s1,
                         const float* __restrict__ s2, const float* __restrict__ s3,
                         const float* __restrict__ s4, const float* __restrict__ s5,
                         unsigned short* __restrict__ dstBase) {
    const float* W;
    switch (blockIdx.y) {
        case 0: W = s0; break; case 1: W = s1; break; case 2: W = s2; break;
        case 3: W = s3; break; case 4: W = s4; break; default: W = s5; break;
    }
    unsigned short* out = dstBase + (size_t)blockIdx.y * 32768;
    int idx = blockIdx.x * 256 + threadIdx.x;
    if (idx >= 16384) return;
    int k = idx >> 7, c = idx & 127;
    float v = W[k * 128 + c];
    unsigned hr = bfr16(v);
    float lof = v - __uint_as_float(hr << 16);
    unsigned lr = bfr16(lof);
    int pos;
    if (blockIdx.y < 2) {
        // 16x16x32: frag f = kt*8+nt ; lane = ((k>>3)&3)<<4 | rho ; elem j = k&7
        int kt = k >> 5, gk = (k >> 3) & 3, j = k & 7;
        int nt = ((c >> 5) << 1) | ((c >> 2) & 1);
        int rho = (((c >> 3) & 3) << 2) | (c & 3);
        int lane = (gk << 4) | rho;
        pos = (kt * 8 + nt) * 512 + lane * 8 + j;
    } else {
        // 32x32x16: c -> (ktc, hc, jc); slot reg = ((ktc&1)<<3)|jc, n = ktc>>1;
        // A-row m = (reg&3)+8*(reg>>2)+4*hc ; lane = ((k>>3)&1)<<5 | m ; frag f = (k>>4)*4+n
        int kk = k >> 4, gk = (k >> 3) & 1, jj = k & 7;
        int ktc = c >> 4, hc = (c >> 3) & 1, jc = c & 7;
        int n = ktc >> 1;
        int reg = ((ktc & 1) << 3) | jc;
        int m = (reg & 3) + 8 * (reg >> 2) + 4 * hc;
        int lane = (gk << 5) | m;
        pos = (kk * 4 + n) * 512 + lane * 8 + jj;
    }
    out[pos] = (unsigned short)hr;
    out[16384 + pos] = (unsigned short)lr;
}

// ---- gather aggregate: out[i] = relu(bias + dinv[i]*(hp[i] + sum_in hp[s])).
// hp = bf16 hi-plane (2 B/chan). 4 nodes/wave, 16 lanes x 8 chans; 8-deep unroll.
__global__ __launch_bounds__(256)
void gather4_k(const unsigned short* __restrict__ hp, const float* __restrict__ dinv,
               const int* __restrict__ rowptr, const int* __restrict__ deg,
               const int* __restrict__ csr, const float* __restrict__ bias,
               unsigned* __restrict__ out, int N)
{
    int tid = threadIdx.x;
    int lane = tid & 63;
    int grp = lane >> 4, cl = lane & 15;
    int i = blockIdx.x * 16 + (tid >> 6) * 4 + grp;
    if (i >= N) return;
    int c8 = cl * 8;
    uint4 p = *(const uint4*)(hp + (size_t)i * 128 + c8);
    float a0 = lo16f(p.x), a1 = hi16f(p.x), a2 = lo16f(p.y), a3 = hi16f(p.y);
    float a4 = lo16f(p.z), a5 = hi16f(p.z), a6 = lo16f(p.w), a7 = hi16f(p.w);
    int beg = rowptr[i], dg = deg[i];
    int j = 0;
    for (; j + 7 < dg; j += 8) {
        uint4 q[8];
        #pragma unroll
        for (int u = 0; u < 8; u++) {
            int su = csr[beg + j + u];
            q[u] = *(const uint4*)(hp + (size_t)su * 128 + c8);
        }
        #pragma unroll
        for (int u = 0; u < 8; u++) {
            a0 += lo16f(q[u].x); a1 += hi16f(q[u].x);
            a2 += lo16f(q[u].y); a3 += hi16f(q[u].y);
            a4 += lo16f(q[u].z); a5 += hi16f(q[u].z);
            a6 += lo16f(q[u].w); a7 += hi16f(q[u].w);
        }
    }
    for (; j + 3 < dg; j += 4) {
        uint4 q[4];
        #pragma unroll
        for (int u = 0; u < 4; u++) {
            int su = csr[beg + j + u];
            q[u] = *(const uint4*)(hp + (size_t)su * 128 + c8);
        }
        #pragma unroll
        for (int u = 0; u < 4; u++) {
            a0 += lo16f(q[u].x); a1 += hi16f(q[u].x);
            a2 += lo16f(q[u].y); a3 += hi16f(q[u].y);
            a4 += lo16f(q[u].z); a5 += hi16f(q[u].z);
            a6 += lo16f(q[u].w); a7 += hi16f(q[u].w);
        }
    }
    for (; j < dg; j++) {
        int s0 = csr[beg + j];
        uint4 q0 = *(const uint4*)(hp + (size_t)s0 * 128 + c8);
        a0 += lo16f(q0.x); a1 += hi16f(q0.x); a2 += lo16f(q0.y); a3 += hi16f(q0.y);
        a4 += lo16f(q0.z); a5 += hi16f(q0.z); a6 += lo16f(q0.w); a7 += hi16f(q0.w);
    }
    float di = dinv[i];
    float4 bv0 = *(const float4*)(bias + c8);
    float4 bv1 = *(const float4*)(bias + c8 + 4);
    uint4 o0, o1;
    o0.x = pack_bf2(fmaxf(bv0.x + di * a0, 0.f));
    o0.y = pack_bf2(fmaxf(bv0.y + di * a1, 0.f));
    o0.z = pack_bf2(fmaxf(bv0.z + di * a2, 0.f));
    o0.w = pack_bf2(fmaxf(bv0.w + di * a3, 0.f));
    o1.x = pack_bf2(fmaxf(bv1.x + di * a4, 0.f));
    o1.y = pack_bf2(fmaxf(bv1.y + di * a5, 0.f));
    o1.z = pack_bf2(fmaxf(bv1.z + di * a6, 0.f));
    o1.w = pack_bf2(fmaxf(bv1.w + di * a7, 0.f));
    *(uint4*)(out + (size_t)i * 128 + c8) = o0;
    *(uint4*)(out + (size_t)i * 128 + c8 + 4) = o1;
}

// ---- layer GEMM (16x16 path, round-8 verified): Chp = dinv ⊙ (A @ W) as bf16 hi-plane.
template<int AMODE>   // 0: A fp32 ; 1: A packed split-bf16
__global__ __launch_bounds__(512)
void rowgemm_k(const void* __restrict__ Asrc, const unsigned short* __restrict__ Wp,
               const float* __restrict__ rowScale, unsigned short* __restrict__ CoutHi, int M)
{
    __shared__ __align__(16) unsigned short smw[32768];
    const int t = threadIdx.x, lane = t & 63, wave = t >> 6;
    const int base = blockIdx.x * 128 + wave * 16;
    const int s = lane & 15, g = lane >> 4, kg = g * 8;
    const int arow = base + s;
    const int rowc = (arow < M) ? arow : (M - 1);

    stage_w512(smw, Wp, t);

    bf16x8 yh[4], yl[4];
    #pragma unroll
    for (int kt = 0; kt < 4; kt++) {
        if (AMODE == 1)
            frag_from_packed((const unsigned*)Asrc + (size_t)rowc * 128 + kt * 32 + kg, yh[kt], yl[kt]);
        else
            frag_from_f32((const float*)Asrc + (size_t)rowc * 128 + kt * 32 + kg, yh[kt], yl[kt]);
    }
    __syncthreads();

    f32x4 acc[8];
    #pragma unroll
    for (int nt = 0; nt < 8; nt++) acc[nt] = (f32x4){0.f, 0.f, 0.f, 0.f};

    #pragma unroll
    for (int kt = 0; kt < 4; kt++) {
        #pragma unroll
        for (int nt = 0; nt < 8; nt++) {
            bf16x8 whi, wlo;
            wfrag_lds(smw, kt * 8 + nt, lane, whi, wlo);
            MFMA3(acc[nt], whi, wlo, yh[kt], yl[kt]);
        }
    }

    if (arow < M) {
        float sc = rowScale[arow];
        #pragma unroll
        for (int nt = 0; nt < 8; nt++) {
            int cbase = 32 * (nt >> 1) + 8 * g + 4 * (nt & 1);
            ushort4 o;
            o.x = (unsigned short)bfr16(acc[nt][0] * sc);
            o.y = (unsigned short)bfr16(acc[nt][1] * sc);
            o.z = (unsigned short)bfr16(acc[nt][2] * sc);
            o.w = (unsigned short)bfr16(acc[nt][3] * sc);
            *(ushort4*)(CoutHi + (size_t)arow * 128 + cbase) = o;
        }
    }
}

// ---- fused predict MLP (32x32x16 path): gather xi/xj -> y1 -> y2 -> y3 -> dot -> out.
// 32 samples/wave, 8 waves (256 samples/block). Weights staged in LDS per layer.
__global__ __launch_bounds__(512)
void mlp_k(const unsigned* __restrict__ X, const int* __restrict__ psrc, const int* __restrict__ pdst,
           const unsigned short* __restrict__ W1a, const unsigned short* __restrict__ W1b,
           const float* __restrict__ b1, const unsigned short* __restrict__ W2p,
           const float* __restrict__ b2, const unsigned short* __restrict__ W3p,
           const float* __restrict__ b3, const float* __restrict__ w4,
           const float* __restrict__ b4p, float* __restrict__ out, int M)
{
    __shared__ __align__(16) unsigned short smw[32768];
    const int t = threadIdx.x, lane = t & 63, wave = t >> 6;
    const int base = blockIdx.x * 256 + wave * 32;
    const int s = lane & 31, h8 = (lane >> 5) * 8;
    const int arow = base + s;
    const int rowc = (arow < M) ? arow : (M - 1);
    const int si = psrc[rowc], sj = pdst[rowc];

    f32x16 acc1[4];
    #pragma unroll
    for (int nt = 0; nt < 4; nt++)
        #pragma unroll
        for (int q = 0; q < 16; q++) acc1[nt][q] = 0.f;

    // ---- phase 1a: xi @ W1a ----
    stage_w512(smw, W1a, t);
    __syncthreads();
    #pragma unroll
    for (int kt = 0; kt < 8; kt++) {
        bf16x8 xh, xl;
        frag_from_packed(X + (size_t)si * 128 + kt * 16 + h8, xh, xl);
        #pragma unroll
        for (int nt = 0; nt < 4; nt++) {
            bf16x8 whi, wlo;
            wfrag_lds(smw, kt * 4 + nt, lane, whi, wlo);
            MFMA3W(acc1[nt], whi, wlo, xh, xl);
        }
    }
    __syncthreads();

    // ---- phase 1b: xj @ W1b ----
    stage_w512(smw, W1b, t);
    __syncthreads();
    #pragma unroll
    for (int kt = 0; kt < 8; kt++) {
        bf16x8 xh, xl;
        frag_from_packed(X + (size_t)sj * 128 + kt * 16 + h8, xh, xl);
        #pragma unroll
        for (int nt = 0; nt < 4; nt++) {
            bf16x8 whi, wlo;
            wfrag_lds(smw, kt * 4 + nt, lane, whi, wlo);
            MFMA3W(acc1[nt], whi, wlo, xh, xl);
        }
    }
    __syncthreads();

    // ---- layer 2: y = relu(acc1 + b1) @ W2 (register relabel transition) ----
    stage_w512(smw, W2p, t);
    __syncthreads();
    f32x16 acc2[4];
    #pragma unroll
    for (int nt = 0; nt < 4; nt++)
        #pragma unroll
        for (int q = 0; q < 16; q++) acc2[nt][q] = 0.f;
    #pragma unroll
    for (int kt = 0; kt < 8; kt++) {
        float4 bva = *(const float4*)(b1 + kt * 16 + h8);
        float4 bvb = *(const float4*)(b1 + kt * 16 + h8 + 4);
        bf16x8 yh, yl;
        trans32(acc1[kt >> 1], (kt & 1) * 8, bva, bvb, yh, yl);
        #pragma unroll
        for (int nt = 0; nt < 4; nt++) {
            bf16x8 whi, wlo;
            wfrag_lds(smw, kt * 4 + nt, lane, whi, wlo);
            MFMA3W(acc2[nt], whi, wlo, yh, yl);
        }
    }
    __syncthreads();

    // ---- layer 3 ----
    stage_w512(smw, W3p, t);
    __syncthreads();
    f32x16 acc3[4];
    #pragma unroll
    for (int nt = 0; nt < 4; nt++)
        #pragma unroll
        for (int q = 0; q < 16; q++) acc3[nt][q] = 0.f;
    #pragma unroll
    for (int kt = 0; kt < 8; kt++) {
        float4 bva = *(const float4*)(b2 + kt * 16 + h8);
        float4 bvb = *(const float4*)(b2 + kt * 16 + h8 + 4);
        bf16x8 yh, yl;
        trans32(acc2[kt >> 1], (kt & 1) * 8, bva, bvb, yh, yl);
        #pragma unroll
        for (int nt = 0; nt < 4; nt++) {
            bf16x8 whi, wlo;
            wfrag_lds(smw, kt * 4 + nt, lane, whi, wlo);
            MFMA3W(acc3[nt], whi, wlo, yh, yl);
        }
    }

    // ---- final: out = relu( sum_c relu(y3[c]) * w4[c] + b4 ) ----
    // slot c: regs 0..7 -> c = 32n + h8 + j ; regs 8..15 -> c = 32n + 16 + h8 + j
    float p = 0.f;
    #pragma unroll
    for (int nt = 0; nt < 4; nt++) {
        int c1 = 32 * nt + h8;
        int c2 = 32 * nt + 16 + h8;
        float4 b3a = *(const float4*)(b3 + c1);
        float4 b3b = *(const float4*)(b3 + c1 + 4);
        float4 b3c = *(const float4*)(b3 + c2);
        float4 b3d = *(const float4*)(b3 + c2 + 4);
        float4 w4a = *(const float4*)(w4 + c1);
        float4 w4b = *(const float4*)(w4 + c1 + 4);
        float4 w4c = *(const float4*)(w4 + c2);
        float4 w4d = *(const float4*)(w4 + c2 + 4);
        p += fmaxf(acc3[nt][0]  + b3a.x, 0.f) * w4a.x;
        p += fmaxf(acc3[nt][1]  + b3a.y, 0.f) * w4a.y;
        p += fmaxf(acc3[nt][2]  + b3a.z, 0.f) * w4a.z;
        p += fmaxf(acc3[nt][3]  + b3a.w, 0.f) * w4a.w;
        p += fmaxf(acc3[nt][4]  + b3b.x, 0.f) * w4b.x;
        p += fmaxf(acc3[nt][5]  + b3b.y, 0.f) * w4b.y;
        p += fmaxf(acc3[nt][6]  + b3b.z, 0.f) * w4b.z;
        p += fmaxf(acc3[nt][7]  + b3b.w, 0.f) * w4b.w;
        p += fmaxf(acc3[nt][8]  + b3c.x, 0.f) * w4c.x;
        p += fmaxf(acc3[nt][9]  + b3c.y, 0.f) * w4c.y;
        p += fmaxf(acc3[nt][10] + b3c.z, 0.f) * w4c.z;
        p += fmaxf(acc3[nt][11] + b3c.w, 0.f) * w4c.w;
        p += fmaxf(acc3[nt][12] + b3d.x, 0.f) * w4d.x;
        p += fmaxf(acc3[nt][13] + b3d.y, 0.f) * w4d.y;
        p += fmaxf(acc3[nt][14] + b3d.z, 0.f) * w4d.z;
        p += fmaxf(acc3[nt][15] + b3d.w, 0.f) * w4d.w;
    }
    p += __shfl_xor(p, 32, 64);
    if (lane < 32 && arow < M) out[arow] = fmaxf(p + b4p[0], 0.f);
}

extern "C" void kernel_launch(void* const* d_in, const int* in_sizes, int n_in,
                              void* d_out, int out_size, void* d_ws, size_t ws_size,
                              hipStream_t stream)
{
    const float* x   = (const float*)d_in[0];
    const int*   ei  = (const int*)d_in[2];
    const int*   pei = (const int*)d_in[3];
    const float* W1  = (const float*)d_in[4];
    const float* b1  = (const float*)d_in[5];
    const float* W2  = (const float*)d_in[6];
    const float* b2  = (const float*)d_in[7];
    // d_in[8..11] = edge_mlp weights: dead w.r.t. output, skipped
    const float* pW1 = (const float*)d_in[12];
    const float* pb1 = (const float*)d_in[13];
    const float* pW2 = (const float*)d_in[14];
    const float* pb2 = (const float*)d_in[15];
    const float* pW3 = (const float*)d_in[16];
    const float* pb3 = (const float*)d_in[17];
    const float* pW4 = (const float*)d_in[18];
    const float* pb4 = (const float*)d_in[19];

    const int N  = in_sizes[0] / 128;
    const int E  = in_sizes[2] / 2;
    const int EP = in_sizes[3] / 2;
    const int Npad = (N + 255) & ~255;

    float*    ws     = (float*)d_ws;
    float*    dinv   = ws;                                  // Npad
    unsigned* bufA   = (unsigned*)(ws + Npad);              // N*128 u32 (hp hi-plane uses half)
    unsigned* bufB   = bufA + (size_t)N * 128;              // N*128 packed split-bf16
    int*      deg    = (int*)(bufB + (size_t)N * 128);      // Npad
    int*      rowptr = deg + Npad;                          // Npad
    int*      cursor = rowptr + Npad;                       // Npad
    int*      csr    = cursor + Npad;                       // E
    int*      bsum   = csr + E;                             // 512
    size_t wpOff = ((size_t)(bsum + 512) + 15) & ~(size_t)15;
    unsigned short* wp = (unsigned short*)wpOff;            // 6 x 32768 u16
    unsigned short* W1p  = wp;
    unsigned short* W2p  = wp + 32768;
    unsigned short* P1Ap = wp + 2 * 32768;
    unsigned short* P1Bp = wp + 3 * 32768;
    unsigned short* P2p  = wp + 4 * 32768;
    unsigned short* P3p  = wp + 5 * 32768;
    unsigned short* hpHi = (unsigned short*)bufA;           // bf16 hi-plane, N*128 u16
    float* out = (float*)d_out;

    const int* esrc = ei;
    const int* edst = ei + E;
    const int* psrc = pei;
    const int* pdst = pei + EP;

    const int nb = (N + 255) / 256;
    const int gN = (N + 255) / 256;
    const int gE = (E + 255) / 256;
    const int gT = (N + 127) / 128;
    const int gP = (EP + 255) / 256;    // 256 samples per block (8 waves x 32)
    const int gG = (N + 15) / 16;

    // ---- CSR build + dinv ----
    zero2_k<<<gN, 256, 0, stream>>>(deg, cursor, N);
    hist_k<<<gE, 256, 0, stream>>>(edst, deg, E);
    scan1_k<<<nb, 256, 0, stream>>>(deg, rowptr, bsum, dinv, N);
    scan2_k<<<1, 512, 0, stream>>>(bsum, nb);
    scan3_k<<<gN, 256, 0, stream>>>(rowptr, bsum, N);
    place_k<<<gE, 256, 0, stream>>>(esrc, edst, rowptr, cursor, csr, E);

    // ---- weight prep (dual format) ----
    wprep6_k<<<dim3(64, 6), 256, 0, stream>>>(W1, W2, pW1, pW1 + 128 * 128, pW2, pW3, wp);

    // ---- layer 0: hp1 = dinv ⊙ (x@W1) [bf16 hi-plane]; x1r = relu(agg + b1) [packed] ----
    rowgemm_k<0><<<gT, 512, 0, stream>>>(x, W1p, dinv, hpHi, N);
    gather4_k<<<gG, 256, 0, stream>>>(hpHi, dinv, rowptr, deg, csr, b1, bufB, N);

    // ---- layer 1 ----
    rowgemm_k<1><<<gT, 512, 0, stream>>>(bufB, W2p, dinv, hpHi, N);
    gather4_k<<<gG, 256, 0, stream>>>(hpHi, dinv, rowptr, deg, csr, b2, bufB, N);

    // ---- fused predict MLP (32x32 path, 8 waves/block) ----
    mlp_k<<<gP, 512, 0, stream>>>(bufB, psrc, pdst, P1Ap, P1Bp, pb1, P2p, pb2, P3p, pb3,
                                  pW4, pb4, out, EP);
}

// Round 12
// 211.105 us; speedup vs baseline: 1.3241x; 1.1787x over previous
//
#include <hip/hip_runtime.h>

typedef __attribute__((ext_vector_type(8))) short bf16x8;
typedef __attribute__((ext_vector_type(4))) float f32x4;
typedef __attribute__((ext_vector_type(16))) float f32x16;

// ---- bf16 helpers ----
__device__ __forceinline__ unsigned bfr16(float x) {            // RNE fp32->bf16 bits
    unsigned u = __float_as_uint(x);
    return (u + 0x7fffu + ((u >> 16) & 1u)) >> 16;
}
// decode two bf16 packed in one u32 (memory order: low u16 = even channel)
__device__ __forceinline__ float lo16f(unsigned u) { return __uint_as_float(u << 16); }
__device__ __forceinline__ float hi16f(unsigned u) { return __uint_as_float(u & 0xffff0000u); }

union U8 { bf16x8 v; unsigned u[4]; };

// fragment from 8 fp32 (round each to bf16)
__device__ __forceinline__ void frag_from_f32(const float* fp, bf16x8& hi) {
    float4 f0 = *(const float4*)fp;
    float4 f1 = *(const float4*)(fp + 4);
    float fv[8] = {f0.x, f0.y, f0.z, f0.w, f1.x, f1.y, f1.z, f1.w};
    U8 H;
    #pragma unroll
    for (int p = 0; p < 4; p++)
        H.u[p] = bfr16(fv[2 * p]) | (bfr16(fv[2 * p + 1]) << 16);
    hi = H.v;
}

// stage one prepped weight matrix (32 KB bf16) into LDS
__device__ __forceinline__ void stage_w512(unsigned short* sm, const unsigned short* Wp, int t) {
    const uint4* src = (const uint4*)Wp;
    uint4* dst = (uint4*)sm;
    #pragma unroll
    for (int p = 0; p < 4; p++) dst[t + p * 512] = src[t + p * 512];
}
__device__ __forceinline__ void stage_w256(unsigned short* sm, const unsigned short* Wp, int t) {
    const uint4* src = (const uint4*)Wp;
    uint4* dst = (uint4*)sm;
    #pragma unroll
    for (int p = 0; p < 8; p++) dst[t + p * 256] = src[t + p * 256];
}

__device__ __forceinline__ bf16x8 wfrag_lds(const unsigned short* sm, int f, int lane) {
    return *(const bf16x8*)(sm + f * 512 + lane * 8);
}

// ---- 16x16 path slot map (GCN layers): chan(nt, rho=4g+r) = 32*(nt>>1)+8*g+4*(nt&1)+r
// ---- 32x32 path slot map (MLP): D slot (n, reg, h=lane>>5) <-> true channel
//      c = kt*16 + h*8 + j  with kt = 2n + (reg>>3), j = reg&7
//      => next-layer B-frag(kt) = acc[kt>>1][(kt&1)*8 + j] (register relabel)

// 32x32 layer transition: y(kt) fragment from acc half + bias (+relu), bf16
__device__ __forceinline__ bf16x8 trans32(const f32x16& A, int sb, float4 bva, float4 bvb) {
    float v0 = fmaxf(A[sb + 0] + bva.x, 0.f);
    float v1 = fmaxf(A[sb + 1] + bva.y, 0.f);
    float v2 = fmaxf(A[sb + 2] + bva.z, 0.f);
    float v3 = fmaxf(A[sb + 3] + bva.w, 0.f);
    float v4 = fmaxf(A[sb + 4] + bvb.x, 0.f);
    float v5 = fmaxf(A[sb + 5] + bvb.y, 0.f);
    float v6 = fmaxf(A[sb + 6] + bvb.z, 0.f);
    float v7 = fmaxf(A[sb + 7] + bvb.w, 0.f);
    U8 H;
    H.u[0] = bfr16(v0) | (bfr16(v1) << 16);
    H.u[1] = bfr16(v2) | (bfr16(v3) << 16);
    H.u[2] = bfr16(v4) | (bfr16(v5) << 16);
    H.u[3] = bfr16(v6) | (bfr16(v7) << 16);
    return H.v;
}

// ---------------- CSR build ----------------

__global__ void zero2_k(int* __restrict__ a, int* __restrict__ b, int n) {
    int i = blockIdx.x * blockDim.x + threadIdx.x;
    if (i < n) { a[i] = 0; b[i] = 0; }
}

__global__ void hist_k(const int* __restrict__ dst, int* __restrict__ deg, int E) {
    int e = blockIdx.x * blockDim.x + threadIdx.x;
    if (e < E) atomicAdd(&deg[dst[e]], 1);
}

__global__ void scan1_k(const int* __restrict__ deg, int* __restrict__ rowptr,
                        int* __restrict__ bsum, float* __restrict__ dinv, int n) {
    __shared__ int s[256];
    int tid = threadIdx.x;
    int i = blockIdx.x * 256 + tid;
    int v = (i < n) ? deg[i] : 0;
    s[tid] = v;
    __syncthreads();
    #pragma unroll
    for (int off = 1; off < 256; off <<= 1) {
        int t = (tid >= off) ? s[tid - off] : 0;
        __syncthreads();
        s[tid] += t;
        __syncthreads();
    }
    if (i < n) {
        rowptr[i] = s[tid] - v;
        dinv[i] = rsqrtf((float)(v + 1));
    }
    if (tid == 255) bsum[blockIdx.x] = s[255];
}

__global__ void scan2_k(int* __restrict__ bsum, int nb) {
    __shared__ int s[512];
    int tid = threadIdx.x;
    int v = (tid < nb) ? bsum[tid] : 0;
    s[tid] = v;
    __syncthreads();
    #pragma unroll
    for (int off = 1; off < 512; off <<= 1) {
        int t = (tid >= off) ? s[tid - off] : 0;
        __syncthreads();
        s[tid] += t;
        __syncthreads();
    }
    if (tid < nb) bsum[tid] = s[tid] - v;
}

__global__ void scan3_k(int* __restrict__ rowptr, const int* __restrict__ bsum, int n) {
    int i = blockIdx.x * blockDim.x + threadIdx.x;
    if (i < n) rowptr[i] += bsum[i >> 8];
}

__global__ void place_k(const int* __restrict__ src, const int* __restrict__ dst,
                        const int* __restrict__ rowptr, int* __restrict__ cursor,
                        int* __restrict__ csr, int E) {
    int e = blockIdx.x * blockDim.x + threadIdx.x;
    if (e < E) {
        int d = dst[e];
        int pos = rowptr[d] + atomicAdd(&cursor[d], 1);
        csr[pos] = src[e];
    }
}

// ---- weight prep (bf16 single plane, 16384 u16 per matrix).
// y=0,1 -> 16x16 A-frag format (GCN). y=2..5 -> 32x32 A-frag format (MLP).
__global__ void wprep6_k(const float* __restrict__ s0, const float* __restrict__ s1,
                         const float* __restrict__ s2, const float* __restrict__ s3,
                         const float* __restrict__ s4, const float* __restrict__ s5,
                         unsigned short* __restrict__ dstBase) {
    const float* W;
    switch (blockIdx.y) {
        case 0: W = s0; break; case 1: W = s1; break; case 2: W = s2; break;
        case 3: W = s3; break; case 4: W = s4; break; default: W = s5; break;
    }
    unsigned short* out = dstBase + (size_t)blockIdx.y * 16384;
    int idx = blockIdx.x * 256 + threadIdx.x;
    if (idx >= 16384) return;
    int k = idx >> 7, c = idx & 127;
    unsigned hr = bfr16(W[k * 128 + c]);
    int pos;
    if (blockIdx.y < 2) {
        // 16x16x32: frag f = kt*8+nt ; lane = ((k>>3)&3)<<4 | rho ; elem j = k&7
        int kt = k >> 5, gk = (k >> 3) & 3, j = k & 7;
        int nt = ((c >> 5) << 1) | ((c >> 2) & 1);
        int rho = (((c >> 3) & 3) << 2) | (c & 3);
        int lane = (gk << 4) | rho;
        pos = (kt * 8 + nt) * 512 + lane * 8 + j;
    } else {
        // 32x32x16: c -> (ktc, hc, jc); slot reg = ((ktc&1)<<3)|jc, n = ktc>>1;
        // A-row m = (reg&3)+8*(reg>>2)+4*hc ; lane = ((k>>3)&1)<<5 | m ; frag f = (k>>4)*4+n
        int kk = k >> 4, gk = (k >> 3) & 1, jj = k & 7;
        int ktc = c >> 4, hc = (c >> 3) & 1, jc = c & 7;
        int n = ktc >> 1;
        int reg = ((ktc & 1) << 3) | jc;
        int m = (reg & 3) + 8 * (reg >> 2) + 4 * hc;
        int lane = (gk << 5) | m;
        pos = (kk * 4 + n) * 512 + lane * 8 + jj;
    }
    out[pos] = (unsigned short)hr;
}

// ---- gather aggregate: out[i] = relu(bias + dinv[i]*(hp[i] + sum_in hp[s])), bf16 plane.
// hp = bf16 plane (2 B/chan). 4 nodes/wave, 16 lanes x 8 chans; 8-deep unroll.
__global__ __launch_bounds__(256)
void gather4_k(const unsigned short* __restrict__ hp, const float* __restrict__ dinv,
               const int* __restrict__ rowptr, const int* __restrict__ deg,
               const int* __restrict__ csr, const float* __restrict__ bias,
               unsigned short* __restrict__ out, int N)
{
    int tid = threadIdx.x;
    int lane = tid & 63;
    int grp = lane >> 4, cl = lane & 15;
    int i = blockIdx.x * 16 + (tid >> 6) * 4 + grp;
    if (i >= N) return;
    int c8 = cl * 8;
    uint4 p = *(const uint4*)(hp + (size_t)i * 128 + c8);
    float a0 = lo16f(p.x), a1 = hi16f(p.x), a2 = lo16f(p.y), a3 = hi16f(p.y);
    float a4 = lo16f(p.z), a5 = hi16f(p.z), a6 = lo16f(p.w), a7 = hi16f(p.w);
    int beg = rowptr[i], dg = deg[i];
    int j = 0;
    for (; j + 7 < dg; j += 8) {
        uint4 q[8];
        #pragma unroll
        for (int u = 0; u < 8; u++) {
            int su = csr[beg + j + u];
            q[u] = *(const uint4*)(hp + (size_t)su * 128 + c8);
        }
        #pragma unroll
        for (int u = 0; u < 8; u++) {
            a0 += lo16f(q[u].x); a1 += hi16f(q[u].x);
            a2 += lo16f(q[u].y); a3 += hi16f(q[u].y);
            a4 += lo16f(q[u].z); a5 += hi16f(q[u].z);
            a6 += lo16f(q[u].w); a7 += hi16f(q[u].w);
        }
    }
    for (; j + 3 < dg; j += 4) {
        uint4 q[4];
        #pragma unroll
        for (int u = 0; u < 4; u++) {
            int su = csr[beg + j + u];
            q[u] = *(const uint4*)(hp + (size_t)su * 128 + c8);
        }
        #pragma unroll
        for (int u = 0; u < 4; u++) {
            a0 += lo16f(q[u].x); a1 += hi16f(q[u].x);
            a2 += lo16f(q[u].y); a3 += hi16f(q[u].y);
            a4 += lo16f(q[u].z); a5 += hi16f(q[u].z);
            a6 += lo16f(q[u].w); a7 += hi16f(q[u].w);
        }
    }
    for (; j < dg; j++) {
        int s0 = csr[beg + j];
        uint4 q0 = *(const uint4*)(hp + (size_t)s0 * 128 + c8);
        a0 += lo16f(q0.x); a1 += hi16f(q0.x); a2 += lo16f(q0.y); a3 += hi16f(q0.y);
        a4 += lo16f(q0.z); a5 += hi16f(q0.z); a6 += lo16f(q0.w); a7 += hi16f(q0.w);
    }
    float di = dinv[i];
    float4 bv0 = *(const float4*)(bias + c8);
    float4 bv1 = *(const float4*)(bias + c8 + 4);
    uint4 o;
    o.x = bfr16(fmaxf(bv0.x + di * a0, 0.f)) | (bfr16(fmaxf(bv0.y + di * a1, 0.f)) << 16);
    o.y = bfr16(fmaxf(bv0.z + di * a2, 0.f)) | (bfr16(fmaxf(bv0.w + di * a3, 0.f)) << 16);
    o.z = bfr16(fmaxf(bv1.x + di * a4, 0.f)) | (bfr16(fmaxf(bv1.y + di * a5, 0.f)) << 16);
    o.w = bfr16(fmaxf(bv1.z + di * a6, 0.f)) | (bfr16(fmaxf(bv1.w + di * a7, 0.f)) << 16);
    *(uint4*)(out + (size_t)i * 128 + c8) = o;
}

// ---- layer GEMM (16x16 path): Chp = dinv ⊙ (A @ W) as bf16 plane. 1 MFMA/frag. ----
template<int AMODE>   // 0: A fp32 ; 1: A bf16 plane
__global__ __launch_bounds__(512)
void rowgemm_k(const void* __restrict__ Asrc, const unsigned short* __restrict__ Wp,
               const float* __restrict__ rowScale, unsigned short* __restrict__ CoutHi, int M)
{
    __shared__ __align__(16) unsigned short smw[16384];   // 32 KB: one bf16 weight matrix
    const int t = threadIdx.x, lane = t & 63, wave = t >> 6;
    const int base = blockIdx.x * 128 + wave * 16;
    const int s = lane & 15, g = lane >> 4, kg = g * 8;
    const int arow = base + s;
    const int rowc = (arow < M) ? arow : (M - 1);

    stage_w512(smw, Wp, t);

    bf16x8 yh[4];
    #pragma unroll
    for (int kt = 0; kt < 4; kt++) {
        if (AMODE == 1)
            yh[kt] = *(const bf16x8*)((const unsigned short*)Asrc + (size_t)rowc * 128 + kt * 32 + kg);
        else
            frag_from_f32((const float*)Asrc + (size_t)rowc * 128 + kt * 32 + kg, yh[kt]);
    }
    __syncthreads();

    f32x4 acc[8];
    #pragma unroll
    for (int nt = 0; nt < 8; nt++) acc[nt] = (f32x4){0.f, 0.f, 0.f, 0.f};

    #pragma unroll
    for (int kt = 0; kt < 4; kt++) {
        #pragma unroll
        for (int nt = 0; nt < 8; nt++) {
            bf16x8 whi = wfrag_lds(smw, kt * 8 + nt, lane);
            acc[nt] = __builtin_amdgcn_mfma_f32_16x16x32_bf16(whi, yh[kt], acc[nt], 0, 0, 0);
        }
    }

    if (arow < M) {
        float sc = rowScale[arow];
        #pragma unroll
        for (int nt = 0; nt < 8; nt++) {
            int cbase = 32 * (nt >> 1) + 8 * g + 4 * (nt & 1);
            ushort4 o;
            o.x = (unsigned short)bfr16(acc[nt][0] * sc);
            o.y = (unsigned short)bfr16(acc[nt][1] * sc);
            o.z = (unsigned short)bfr16(acc[nt][2] * sc);
            o.w = (unsigned short)bfr16(acc[nt][3] * sc);
            *(ushort4*)(CoutHi + (size_t)arow * 128 + cbase) = o;
        }
    }
}

// ---- fused predict MLP (32x32x16, bf16): gather xi/xj -> y1 -> y2 -> y3 -> dot -> out.
// 32 samples/wave, 4 waves (128 samples/block). 32KB LDS weight staging per layer.
__global__ __launch_bounds__(256)
void mlp_k(const unsigned short* __restrict__ X, const int* __restrict__ psrc, const int* __restrict__ pdst,
           const unsigned short* __restrict__ W1a, const unsigned short* __restrict__ W1b,
           const float* __restrict__ b1, const unsigned short* __restrict__ W2p,
           const float* __restrict__ b2, const unsigned short* __restrict__ W3p,
           const float* __restrict__ b3, const float* __restrict__ w4,
           const float* __restrict__ b4p, float* __restrict__ out, int M)
{
    __shared__ __align__(16) unsigned short smw[16384];
    const int t = threadIdx.x, lane = t & 63, wave = t >> 6;
    const int base = blockIdx.x * 128 + wave * 32;
    const int s = lane & 31, h8 = (lane >> 5) * 8;
    const int arow = base + s;
    const int rowc = (arow < M) ? arow : (M - 1);
    const int si = psrc[rowc], sj = pdst[rowc];

    f32x16 acc1[4];
    #pragma unroll
    for (int nt = 0; nt < 4; nt++)
        #pragma unroll
        for (int q = 0; q < 16; q++) acc1[nt][q] = 0.f;

    // ---- phase 1a: xi @ W1a ----
    stage_w256(smw, W1a, t);
    __syncthreads();
    #pragma unroll
    for (int kt = 0; kt < 8; kt++) {
        bf16x8 xh = *(const bf16x8*)(X + (size_t)si * 128 + kt * 16 + h8);
        #pragma unroll
        for (int nt = 0; nt < 4; nt++) {
            bf16x8 whi = wfrag_lds(smw, kt * 4 + nt, lane);
            acc1[nt] = __builtin_amdgcn_mfma_f32_32x32x16_bf16(whi, xh, acc1[nt], 0, 0, 0);
        }
    }
    __syncthreads();

    // ---- phase 1b: xj @ W1b ----
    stage_w256(smw, W1b, t);
    __syncthreads();
    #pragma unroll
    for (int kt = 0; kt < 8; kt++) {
        bf16x8 xh = *(const bf16x8*)(X + (size_t)sj * 128 + kt * 16 + h8);
        #pragma unroll
        for (int nt = 0; nt < 4; nt++) {
            bf16x8 whi = wfrag_lds(smw, kt * 4 + nt, lane);
            acc1[nt] = __builtin_amdgcn_mfma_f32_32x32x16_bf16(whi, xh, acc1[nt], 0, 0, 0);
        }
    }
    __syncthreads();

    // ---- layer 2: y = relu(acc1 + b1) @ W2 (register relabel transition) ----
    stage_w256(smw, W2p, t);
    __syncthreads();
    f32x16 acc2[4];
    #pragma unroll
    for (int nt = 0; nt < 4; nt++)
        #pragma unroll
        for (int q = 0; q < 16; q++) acc2[nt][q] = 0.f;
    #pragma unroll
    for (int kt = 0; kt < 8; kt++) {
        float4 bva = *(const float4*)(b1 + kt * 16 + h8);
        float4 bvb = *(const float4*)(b1 + kt * 16 + h8 + 4);
        bf16x8 yh = trans32(acc1[kt >> 1], (kt & 1) * 8, bva, bvb);
        #pragma unroll
        for (int nt = 0; nt < 4; nt++) {
            bf16x8 whi = wfrag_lds(smw, kt * 4 + nt, lane);
            acc2[nt] = __builtin_amdgcn_mfma_f32_32x32x16_bf16(whi, yh, acc2[nt], 0, 0, 0);
        }
    }
    __syncthreads();

    // ---- layer 3 ----
    stage_w256(smw, W3p, t);
    __syncthreads();
    f32x16 acc3[4];
    #pragma unroll
    for (int nt = 0; nt < 4; nt++)
        #pragma unroll
        for (int q = 0; q < 16; q++) acc3[nt][q] = 0.f;
    #pragma unroll
    for (int kt = 0; kt < 8; kt++) {
        float4 bva = *(const float4*)(b2 + kt * 16 + h8);
        float4 bvb = *(const float4*)(b2 + kt * 16 + h8 + 4);
        bf16x8 yh = trans32(acc2[kt >> 1], (kt & 1) * 8, bva, bvb);
        #pragma unroll
        for (int nt = 0; nt < 4; nt++) {
            bf16x8 whi = wfrag_lds(smw, kt * 4 + nt, lane);
            acc3[nt] = __builtin_amdgcn_mfma_f32_32x32x16_bf16(whi, yh, acc3[nt], 0, 0, 0);
        }
    }

    // ---- final: out = relu( sum_c relu(y3[c]) * w4[c] + b4 ) ----
    // slot c: regs 0..7 -> c = 32n + h8 + j ; regs 8..15 -> c = 32n + 16 + h8 + j
    float p = 0.f;
    #pragma unroll
    for (int nt = 0; nt < 4; nt++) {
        int c1 = 32 * nt + h8;
        int c2 = 32 * nt + 16 + h8;
        float4 b3a = *(const float4*)(b3 + c1);
        float4 b3b = *(const float4*)(b3 + c1 + 4);
        float4 b3c = *(const float4*)(b3 + c2);
        float4 b3d = *(const float4*)(b3 + c2 + 4);
        float4 w4a = *(const float4*)(w4 + c1);
        float4 w4b = *(const float4*)(w4 + c1 + 4);
        float4 w4c = *(const float4*)(w4 + c2);
        float4 w4d = *(const float4*)(w4 + c2 + 4);
        p += fmaxf(acc3[nt][0]  + b3a.x, 0.f) * w4a.x;
        p += fmaxf(acc3[nt][1]  + b3a.y, 0.f) * w4a.y;
        p += fmaxf(acc3[nt][2]  + b3a.z, 0.f) * w4a.z;
        p += fmaxf(acc3[nt][3]  + b3a.w, 0.f) * w4a.w;
        p += fmaxf(acc3[nt][4]  + b3b.x, 0.f) * w4b.x;
        p += fmaxf(acc3[nt][5]  + b3b.y, 0.f) * w4b.y;
        p += fmaxf(acc3[nt][6]  + b3b.z, 0.f) * w4b.z;
        p += fmaxf(acc3[nt][7]  + b3b.w, 0.f) * w4b.w;
        p += fmaxf(acc3[nt][8]  + b3c.x, 0.f) * w4c.x;
        p += fmaxf(acc3[nt][9]  + b3c.y, 0.f) * w4c.y;
        p += fmaxf(acc3[nt][10] + b3c.z, 0.f) * w4c.z;
        p += fmaxf(acc3[nt][11] + b3c.w, 0.f) * w4c.w;
        p += fmaxf(acc3[nt][12] + b3d.x, 0.f) * w4d.x;
        p += fmaxf(acc3[nt][13] + b3d.y, 0.f) * w4d.y;
        p += fmaxf(acc3[nt][14] + b3d.z, 0.f) * w4d.z;
        p += fmaxf(acc3[nt][15] + b3d.w, 0.f) * w4d.w;
    }
    p += __shfl_xor(p, 32, 64);
    if (lane < 32 && arow < M) out[arow] = fmaxf(p + b4p[0], 0.f);
}

extern "C" void kernel_launch(void* const* d_in, const int* in_sizes, int n_in,
                              void* d_out, int out_size, void* d_ws, size_t ws_size,
                              hipStream_t stream)
{
    const float* x   = (const float*)d_in[0];
    const int*   ei  = (const int*)d_in[2];
    const int*   pei = (const int*)d_in[3];
    const float* W1  = (const float*)d_in[4];
    const float* b1  = (const float*)d_in[5];
    const float* W2  = (const float*)d_in[6];
    const float* b2  = (const float*)d_in[7];
    // d_in[8..11] = edge_mlp weights: dead w.r.t. output, skipped
    const float* pW1 = (const float*)d_in[12];
    const float* pb1 = (const float*)d_in[13];
    const float* pW2 = (const float*)d_in[14];
    const float* pb2 = (const float*)d_in[15];
    const float* pW3 = (const float*)d_in[16];
    const float* pb3 = (const float*)d_in[17];
    const float* pW4 = (const float*)d_in[18];
    const float* pb4 = (const float*)d_in[19];

    const int N  = in_sizes[0] / 128;
    const int E  = in_sizes[2] / 2;
    const int EP = in_sizes[3] / 2;
    const int Npad = (N + 255) & ~255;

    float*          ws     = (float*)d_ws;
    float*          dinv   = ws;                                    // Npad
    unsigned short* hpHi   = (unsigned short*)(ws + Npad);          // N*128 u16 (bf16 plane)
    unsigned short* bufB   = hpHi + (size_t)N * 128;                // N*128 u16 (bf16 plane)
    // align following ints to 256B
    size_t ioff = (((size_t)(bufB + (size_t)N * 128)) + 255) & ~(size_t)255;
    int*   deg    = (int*)ioff;                                     // Npad
    int*   rowptr = deg + Npad;                                     // Npad
    int*   cursor = rowptr + Npad;                                  // Npad
    int*   csr    = cursor + Npad;                                  // E
    int*   bsum   = csr + E;                                        // 512
    size_t wpOff = ((size_t)(bsum + 512) + 15) & ~(size_t)15;
    unsigned short* wp = (unsigned short*)wpOff;                    // 6 x 16384 u16
    unsigned short* W1p  = wp;
    unsigned short* W2p  = wp + 16384;
    unsigned short* P1Ap = wp + 2 * 16384;
    unsigned short* P1Bp = wp + 3 * 16384;
    unsigned short* P2p  = wp + 4 * 16384;
    unsigned short* P3p  = wp + 5 * 16384;
    float* out = (float*)d_out;

    const int* esrc = ei;
    const int* edst = ei + E;
    const int* psrc = pei;
    const int* pdst = pei + EP;

    const int nb = (N + 255) / 256;
    const int gN = (N + 255) / 256;
    const int gE = (E + 255) / 256;
    const int gT = (N + 127) / 128;
    const int gP = (EP + 127) / 128;    // 128 samples per block (4 waves x 32)
    const int gG = (N + 15) / 16;

    // ---- CSR build + dinv ----
    zero2_k<<<gN, 256, 0, stream>>>(deg, cursor, N);
    hist_k<<<gE, 256, 0, stream>>>(edst, deg, E);
    scan1_k<<<nb, 256, 0, stream>>>(deg, rowptr, bsum, dinv, N);
    scan2_k<<<1, 512, 0, stream>>>(bsum, nb);
    scan3_k<<<gN, 256, 0, stream>>>(rowptr, bsum, N);
    place_k<<<gE, 256, 0, stream>>>(esrc, edst, rowptr, cursor, csr, E);

    // ---- weight prep (bf16, dual fragment format) ----
    wprep6_k<<<dim3(64, 6), 256, 0, stream>>>(W1, W2, pW1, pW1 + 128 * 128, pW2, pW3, wp);

    // ---- layer 0: hp1 = dinv ⊙ (x@W1) [bf16]; x1r = relu(agg + b1) [bf16] ----
    rowgemm_k<0><<<gT, 512, 0, stream>>>(x, W1p, dinv, hpHi, N);
    gather4_k<<<gG, 256, 0, stream>>>(hpHi, dinv, rowptr, deg, csr, b1, bufB, N);

    // ---- layer 1 ----
    rowgemm_k<1><<<gT, 512, 0, stream>>>(bufB, W2p, dinv, hpHi, N);
    gather4_k<<<gG, 256, 0, stream>>>(hpHi, dinv, rowptr, deg, csr, b2, bufB, N);

    // ---- fused predict MLP (32x32 bf16 path) ----
    mlp_k<<<gP, 256, 0, stream>>>(bufB, psrc, pdst, P1Ap, P1Bp, pb1, P2p, pb2, P3p, pb3,
                                  pW4, pb4, out, EP);
}